// Round 5
// baseline (148.511 us; speedup 1.0000x reference)
//
#include <hip/hip_runtime.h>

// ---------------------------------------------------------------------------
// Attention_43868795961547: LN -> QKV -> MHA(1025 keys) -> proj
// b=8, n=1024, dim=512, heads=8, dh=64. bf16 MFMA, f32 accum.
// Round 5: k_attn split-K 2-way (flash-decoding): 4096 waves, 4 waves/SIMD,
// half the serial chain per wave; LDS end-merge of (m,l,O) pairs.
// ---------------------------------------------------------------------------

typedef __attribute__((ext_vector_type(4))) float f32x4;
typedef __attribute__((ext_vector_type(16))) float f32x16;
typedef __attribute__((ext_vector_type(8))) short bf16x8;

#define MFMA16(a, b, c) __builtin_amdgcn_mfma_f32_16x16x32_bf16(a, b, c, 0, 0, 0)
#define MFMA32(a, b, c) __builtin_amdgcn_mfma_f32_32x32x16_bf16(a, b, c, 0, 0, 0)

#define GLD16(gsrc, ldst)                                                     \
  __builtin_amdgcn_global_load_lds(                                           \
      (const __attribute__((address_space(1))) void*)(gsrc),                  \
      (__attribute__((address_space(3))) void*)(ldst), 16, 0, 0)

// Q pre-scale: dots*0.125 in exp2-domain => fold 0.125*log2(e) into Q.
#define QSCALE 0.18033688011112042f

__device__ __forceinline__ unsigned short f2bf(float f) {
  union { float f; unsigned int u; } c; c.f = f;
  unsigned int u = c.u;
  u += 0x7fffu + ((u >> 16) & 1u);   // RNE
  return (unsigned short)(u >> 16);
}

__device__ __forceinline__ unsigned int cvtpk_bf16(float lo, float hi) {
  unsigned int r;
  asm("v_cvt_pk_bf16_f32 %0, %1, %2" : "=v"(r) : "v"(lo), "v"(hi));
  return r;
}

// ---- kernel 1: tiled transpose+convert weights to bf16 --------------------
__global__ __launch_bounds__(256) void k_prep(const float* __restrict__ w_qkv,
                                              const float* __restrict__ w_out,
                                              unsigned short* __restrict__ wqt,
                                              unsigned short* __restrict__ wot) {
  __shared__ unsigned short t[64][68];
  int blk = blockIdx.x, tid = threadIdx.x;
  const float* src;
  unsigned short* dst;
  int k0, n0, ldin;
  if (blk < 192) {
    int ti = blk / 24, tj = blk % 24;
    k0 = ti * 64; n0 = tj * 64; ldin = 1536;
    src = w_qkv; dst = wqt;
  } else {
    int g = blk - 192;
    int ti = g >> 3, tj = g & 7;
    k0 = ti * 64; n0 = tj * 64; ldin = 512;
    src = w_out; dst = wot;
  }
  int rr = tid >> 4, c4 = (tid & 15) * 4;
  #pragma unroll
  for (int i = 0; i < 4; ++i) {
    int r = i * 16 + rr;
    float4 v = *(const float4*)(src + (size_t)(k0 + r) * ldin + n0 + c4);
    t[c4 + 0][r] = f2bf(v.x);
    t[c4 + 1][r] = f2bf(v.y);
    t[c4 + 2][r] = f2bf(v.z);
    t[c4 + 3][r] = f2bf(v.w);
  }
  __syncthreads();
  #pragma unroll
  for (int i = 0; i < 4; ++i) {
    int r = i * 16 + rr;
    ushort4 w = *(const ushort4*)&t[r][c4];
    *(ushort4*)(dst + (size_t)(n0 + r) * 512 + k0 + c4) = w;
  }
}

// ---- kernel 2: LayerNorm (wave per row) -----------------------------------
__global__ __launch_bounds__(256) void k_ln(const float* __restrict__ img,
                                            const float* __restrict__ tab,
                                            const float* __restrict__ ln_w,
                                            const float* __restrict__ ln_b,
                                            unsigned short* __restrict__ x_bf,
                                            float* __restrict__ t_ln) {
  int wid = threadIdx.x >> 6, lane = threadIdx.x & 63;
  int row = blockIdx.x * 4 + wid;
  if (row >= 8200) return;
  const float* src = (row < 8192) ? img + (size_t)row * 512
                                  : tab + (size_t)(row - 8192) * 512;
  float4 v0 = *(const float4*)(src + lane * 8);
  float4 v1 = *(const float4*)(src + lane * 8 + 4);
  float x[8] = {v0.x, v0.y, v0.z, v0.w, v1.x, v1.y, v1.z, v1.w};
  float s = 0.f, sq = 0.f;
  #pragma unroll
  for (int j = 0; j < 8; ++j) { s += x[j]; sq += x[j] * x[j]; }
  #pragma unroll
  for (int off = 32; off >= 1; off >>= 1) {
    s  += __shfl_xor(s, off);
    sq += __shfl_xor(sq, off);
  }
  float mean = s * (1.0f / 512.0f);
  float var  = sq * (1.0f / 512.0f) - mean * mean;
  float rs = rsqrtf(var + 1e-5f);
  float4 w0 = *(const float4*)(ln_w + lane * 8);
  float4 w1 = *(const float4*)(ln_w + lane * 8 + 4);
  float4 b0 = *(const float4*)(ln_b + lane * 8);
  float4 b1 = *(const float4*)(ln_b + lane * 8 + 4);
  float w[8] = {w0.x, w0.y, w0.z, w0.w, w1.x, w1.y, w1.z, w1.w};
  float bb[8] = {b0.x, b0.y, b0.z, b0.w, b1.x, b1.y, b1.z, b1.w};
  float y[8];
  #pragma unroll
  for (int j = 0; j < 8; ++j) y[j] = (x[j] - mean) * rs * w[j] + bb[j];
  if (row < 8192) {
    bf16x8 o;
    #pragma unroll
    for (int j = 0; j < 8; ++j) o[j] = (short)f2bf(y[j]);
    *(bf16x8*)(x_bf + (size_t)row * 512 + lane * 8) = o;
  } else {
    float* dst = t_ln + (size_t)(row - 8192) * 512 + lane * 8;
    *(float4*)dst       = make_float4(y[0], y[1], y[2], y[3]);
    *(float4*)(dst + 4) = make_float4(y[4], y[5], y[6], y[7]);
  }
}

// ---- kernel 3: tab token k/v (block per batch, coalesced) -----------------
__global__ __launch_bounds__(256) void k_tab(const float* __restrict__ t_ln,
                                             const float* __restrict__ w_tab,
                                             unsigned short* __restrict__ kh,
                                             unsigned short* __restrict__ vt) {
  __shared__ float tl[512];
  int b = blockIdx.x, t = threadIdx.x;
  tl[t] = t_ln[b * 512 + t];
  tl[t + 256] = t_ln[b * 512 + t + 256];
  __syncthreads();
  float s[4] = {0.f, 0.f, 0.f, 0.f};
  for (int k = 0; k < 512; ++k) {
    float a = tl[k];
    #pragma unroll
    for (int i = 0; i < 4; ++i)
      s[i] += a * w_tab[(size_t)k * 1536 + 512 + i * 256 + t];
  }
  #pragma unroll
  for (int i = 0; i < 4; ++i) {
    int g = i * 256 + t;
    int part = g >> 9, hd = g & 511, h = hd >> 6, d = hd & 63;
    int bh = b * 8 + h;
    unsigned short hv = f2bf(s[i]);
    if (part == 0) kh[((size_t)bh * 1056 + 1024) * 64 + d] = hv;
    else           vt[((size_t)bh * 64 + d) * 1056 + 1024] = hv;
  }
}

// ---- kernel 4: QKV GEMM, m97 structure ------------------------------------
__global__ __launch_bounds__(256) void k_qkv(const unsigned short* __restrict__ x_bf,
                                             const unsigned short* __restrict__ wqt,
                                             unsigned short* __restrict__ qh,
                                             unsigned short* __restrict__ kh,
                                             unsigned short* __restrict__ vt) {
  __shared__ unsigned short As[128 * 32];
  __shared__ unsigned short Bs[128 * 32];
  int tid = threadIdx.x;
  int wid = tid >> 6, lane = tid & 63;
  int bm = blockIdx.x & 63, bn = blockIdx.x >> 6;   // 64 x 12
  int r0 = bm * 128, c0 = bn * 128;
  int lr = lane & 15, lk = (lane >> 4) * 8;
  int wr = (wid >> 1) * 64, wc = (wid & 1) * 64;
  int srow = lane >> 2, scol = (lane & 3) * 8;
  const unsigned short* gA0 = x_bf + (size_t)(r0 + (wid * 2 + 0) * 16 + srow) * 512 + scol;
  const unsigned short* gA1 = x_bf + (size_t)(r0 + (wid * 2 + 1) * 16 + srow) * 512 + scol;
  const unsigned short* gB0 = wqt  + (size_t)(c0 + (wid * 2 + 0) * 16 + srow) * 512 + scol;
  const unsigned short* gB1 = wqt  + (size_t)(c0 + (wid * 2 + 1) * 16 + srow) * 512 + scol;
  unsigned short* lA0 = &As[(wid * 2 + 0) * 512];
  unsigned short* lA1 = &As[(wid * 2 + 1) * 512];
  unsigned short* lB0 = &Bs[(wid * 2 + 0) * 512];
  unsigned short* lB1 = &Bs[(wid * 2 + 1) * 512];

  f32x4 acc[4][4];
  #pragma unroll
  for (int mi = 0; mi < 4; ++mi)
    #pragma unroll
    for (int ni = 0; ni < 4; ++ni)
      acc[mi][ni] = (f32x4){0.f, 0.f, 0.f, 0.f};

  for (int k0 = 0; k0 < 512; k0 += 32) {
    GLD16(gA0 + k0, lA0);
    GLD16(gA1 + k0, lA1);
    GLD16(gB0 + k0, lB0);
    GLD16(gB1 + k0, lB1);
    __syncthreads();
    bf16x8 af[4], bfr[4];
    #pragma unroll
    for (int mi = 0; mi < 4; ++mi)
      af[mi] = *(const bf16x8*)&As[(wr + mi * 16 + lr) * 32 + lk];
    #pragma unroll
    for (int ni = 0; ni < 4; ++ni)
      bfr[ni] = *(const bf16x8*)&Bs[(wc + ni * 16 + lr) * 32 + lk];
    #pragma unroll
    for (int mi = 0; mi < 4; ++mi)
      #pragma unroll
      for (int ni = 0; ni < 4; ++ni)
        acc[mi][ni] = MFMA16(af[mi], bfr[ni], acc[mi][ni]);
    __syncthreads();
  }

  #pragma unroll
  for (int ni = 0; ni < 4; ++ni) {
    int col0 = c0 + wc + ni * 16;
    int which = col0 >> 9;
    int hh = (col0 & 511) >> 6;
    int d = (col0 & 63) + lr;
    #pragma unroll
    for (int mi = 0; mi < 4; ++mi)
      #pragma unroll
      for (int reg = 0; reg < 4; ++reg) {
        int row = r0 + wr + mi * 16 + (lane >> 4) * 4 + reg;
        int b = row >> 10, n = row & 1023;
        int bh = b * 8 + hh;
        float v = acc[mi][ni][reg];
        if (which == 0) {
          qh[((size_t)bh * 1024 + n) * 64 + d] = f2bf(v * QSCALE);
        } else if (which == 1) {
          kh[((size_t)bh * 1056 + n) * 64 + d] = f2bf(v);
        } else {
          vt[((size_t)bh * 64 + d) * 1056 + n] = f2bf(v);
        }
      }
  }
}

// ---- kernel 5: flash attention, split-K 2-way + swapped 32x32 MFMA --------
// 1024 blocks, 4 waves/block. Block = (bh, qt-pair); wave wid: pair=wid>>1,
// half=wid&1. half 0 -> key-tiles 0..16, half 1 -> 17..32. End merge of
// (m,l,O) via LDS. XCD swizzle: 16 consecutive swz blocks (one bh) per XCD.
__global__ __launch_bounds__(256) void k_attn(const unsigned short* __restrict__ qh,
                                              const unsigned short* __restrict__ kh,
                                              const unsigned short* __restrict__ vt,
                                              unsigned short* __restrict__ ao) {
  __shared__ float Ob[2][32][64];
  __shared__ float2 ml[2][64];
  int wid = threadIdx.x >> 6, lane = threadIdx.x & 63;
  int bid = blockIdx.x;
  int swz = ((bid & 7) << 7) | (bid >> 3);      // bijective, 1024 % 8 == 0
  int bh = swz >> 4;
  int pair = wid >> 1;
  int kvh = wid & 1;
  int qt = (swz & 15) * 2 + pair;
  int q0 = qt * 32;
  int kt_begin = kvh ? 17 : 0;
  int kt_end   = kvh ? 33 : 17;
  int lq = lane & 31;
  int half = lane >> 5;
  const unsigned short* Q = qh + (size_t)bh * 1024 * 64;
  const unsigned short* K = kh + (size_t)bh * 1056 * 64;
  const unsigned short* V = vt + (size_t)bh * 64 * 1056;

  const unsigned short* qlane = Q + (size_t)(q0 + lq) * 64 + half * 8;
  const unsigned short* klane = K + (size_t)lq * 64 + half * 8;
  const unsigned short* vlane = V + (size_t)lq * 1056 + half * 8;

  bf16x8 qf[4];
  #pragma unroll
  for (int dt = 0; dt < 4; ++dt)
    qf[dt] = *(const bf16x8*)(qlane + dt * 16);

  // K and V register double-buffers (first-tile preload)
  bf16x8 kf[4], kfn[4], vf[4], vfn[4];
  #pragma unroll
  for (int dt = 0; dt < 4; ++dt)
    kf[dt] = *(const bf16x8*)(klane + kt_begin * 2048 + dt * 16);
  vf[0] = *(const bf16x8*)(vlane + kt_begin * 32);
  vf[1] = *(const bf16x8*)(vlane + kt_begin * 32 + 16);
  vf[2] = *(const bf16x8*)(vlane + 32 * 1056 + kt_begin * 32);
  vf[3] = *(const bf16x8*)(vlane + 32 * 1056 + kt_begin * 32 + 16);

  f32x16 o0 = (f32x16)(0.0f), o1 = (f32x16)(0.0f);
  float m = -1e30f, lsum = 0.f;

  for (int kt = kt_begin; kt < kt_end; ++kt) {
    if (kt + 1 < kt_end) {
      #pragma unroll
      for (int dt = 0; dt < 4; ++dt)
        kfn[dt] = *(const bf16x8*)(klane + (kt + 1) * 2048 + dt * 16);
      vfn[0] = *(const bf16x8*)(vlane + (kt + 1) * 32);
      vfn[1] = *(const bf16x8*)(vlane + (kt + 1) * 32 + 16);
      vfn[2] = *(const bf16x8*)(vlane + 32 * 1056 + (kt + 1) * 32);
      vfn[3] = *(const bf16x8*)(vlane + 32 * 1056 + (kt + 1) * 32 + 16);
    }
    f32x16 s = (f32x16)(0.0f);
    __builtin_amdgcn_s_setprio(1);
    #pragma unroll
    for (int dt = 0; dt < 4; ++dt)
      s = MFMA32(kf[dt], qf[dt], s);
    __builtin_amdgcn_s_setprio(0);
    if (kt == 32) {
      #pragma unroll
      for (int reg = 0; reg < 16; ++reg) {
        if (reg == 0) { if (half) s[0] = -1e30f; }
        else s[reg] = -1e30f;
      }
    }
    float pmax = s[0];
    #pragma unroll
    for (int reg = 1; reg < 16; ++reg) pmax = fmaxf(pmax, s[reg]);
    pmax = fmaxf(pmax, __shfl_xor(pmax, 32));
    if (!__all(pmax <= m + 8.0f)) {
      float mnew = fmaxf(m, pmax);
      float al = __builtin_amdgcn_exp2f(m - mnew);
      lsum *= al;
      #pragma unroll
      for (int reg = 0; reg < 16; ++reg) { o0[reg] *= al; o1[reg] *= al; }
      m = mnew;
    }
    float p[16];
    float ls = 0.f;
    #pragma unroll
    for (int reg = 0; reg < 16; ++reg) {
      p[reg] = __builtin_amdgcn_exp2f(s[reg] - m);
      ls += p[reg];
    }
    lsum += ls;
    unsigned int c0x0 = cvtpk_bf16(p[0],  p[1]);
    unsigned int c0x1 = cvtpk_bf16(p[2],  p[3]);
    unsigned int c0y0 = cvtpk_bf16(p[4],  p[5]);
    unsigned int c0y1 = cvtpk_bf16(p[6],  p[7]);
    unsigned int c1x0 = cvtpk_bf16(p[8],  p[9]);
    unsigned int c1x1 = cvtpk_bf16(p[10], p[11]);
    unsigned int c1y0 = cvtpk_bf16(p[12], p[13]);
    unsigned int c1y1 = cvtpk_bf16(p[14], p[15]);
    asm volatile("v_permlane32_swap_b32 %0, %1" : "+v"(c0x0), "+v"(c0y0));
    asm volatile("v_permlane32_swap_b32 %0, %1" : "+v"(c0x1), "+v"(c0y1));
    asm volatile("v_permlane32_swap_b32 %0, %1" : "+v"(c1x0), "+v"(c1y0));
    asm volatile("v_permlane32_swap_b32 %0, %1" : "+v"(c1x1), "+v"(c1y1));
    union { unsigned int w[4]; bf16x8 v; } f0, f1;
    f0.w[0] = c0x0; f0.w[1] = c0x1; f0.w[2] = c0y0; f0.w[3] = c0y1;
    f1.w[0] = c1x0; f1.w[1] = c1x1; f1.w[2] = c1y0; f1.w[3] = c1y1;
    __builtin_amdgcn_s_setprio(1);
    o0 = MFMA32(vf[0], f0.v, o0);
    o0 = MFMA32(vf[1], f1.v, o0);
    o1 = MFMA32(vf[2], f0.v, o1);
    o1 = MFMA32(vf[3], f1.v, o1);
    __builtin_amdgcn_s_setprio(0);
    #pragma unroll
    for (int dt = 0; dt < 4; ++dt) { kf[dt] = kfn[dt]; vf[dt] = vfn[dt]; }
  }
  lsum += __shfl_xor(lsum, 32);

  // --- split-K merge: half 1 publishes state, half 0 merges + stores ------
  if (kvh == 1) {
    #pragma unroll
    for (int r = 0; r < 16; ++r) Ob[pair][r][lane] = o0[r];
    #pragma unroll
    for (int r = 0; r < 16; ++r) Ob[pair][16 + r][lane] = o1[r];
    ml[pair][lane] = make_float2(m, lsum);
  }
  __syncthreads();
  if (kvh == 0) {
    float2 mb = ml[pair][lane];
    float M = fmaxf(m, mb.x);
    float aA = __builtin_amdgcn_exp2f(m - M);
    float aB = __builtin_amdgcn_exp2f(mb.x - M);
    float l = aA * lsum + aB * mb.y;
    float rl = 1.0f / l;
    float aAr = aA * rl, aBr = aB * rl;
    int b = bh >> 3, h = bh & 7;
    unsigned short* aorow = ao + ((size_t)(b * 1024 + q0 + lq)) * 512 + h * 64;
    #pragma unroll
    for (int dt2 = 0; dt2 < 2; ++dt2) {
      #pragma unroll
      for (int g = 0; g < 4; ++g) {
        ushort4 pk;
        float v0 = (dt2 ? o1[4 * g + 0] : o0[4 * g + 0]) * aAr + Ob[pair][dt2 * 16 + 4 * g + 0][lane] * aBr;
        float v1 = (dt2 ? o1[4 * g + 1] : o0[4 * g + 1]) * aAr + Ob[pair][dt2 * 16 + 4 * g + 1][lane] * aBr;
        float v2 = (dt2 ? o1[4 * g + 2] : o0[4 * g + 2]) * aAr + Ob[pair][dt2 * 16 + 4 * g + 2][lane] * aBr;
        float v3 = (dt2 ? o1[4 * g + 3] : o0[4 * g + 3]) * aAr + Ob[pair][dt2 * 16 + 4 * g + 3][lane] * aBr;
        pk.x = f2bf(v0); pk.y = f2bf(v1); pk.z = f2bf(v2); pk.w = f2bf(v3);
        *(ushort4*)(aorow + dt2 * 32 + 8 * g + 4 * half) = pk;
      }
    }
  }
}

// ---- kernel 6: output GEMM + bias, m97 structure --------------------------
__global__ __launch_bounds__(256) void k_out(const unsigned short* __restrict__ ao,
                                             const unsigned short* __restrict__ wot,
                                             const float* __restrict__ b_out,
                                             float* __restrict__ out) {
  __shared__ unsigned short As[128 * 32];
  __shared__ unsigned short Bs[128 * 32];
  int tid = threadIdx.x;
  int wid = tid >> 6, lane = tid & 63;
  int bm = blockIdx.x & 63, bn = blockIdx.x >> 6;   // 64 x 4
  int r0 = bm * 128, c0 = bn * 128;
  int lr = lane & 15, lk = (lane >> 4) * 8;
  int wr = (wid >> 1) * 64, wc = (wid & 1) * 64;
  int srow = lane >> 2, scol = (lane & 3) * 8;
  const unsigned short* gA0 = ao  + (size_t)(r0 + (wid * 2 + 0) * 16 + srow) * 512 + scol;
  const unsigned short* gA1 = ao  + (size_t)(r0 + (wid * 2 + 1) * 16 + srow) * 512 + scol;
  const unsigned short* gB0 = wot + (size_t)(c0 + (wid * 2 + 0) * 16 + srow) * 512 + scol;
  const unsigned short* gB1 = wot + (size_t)(c0 + (wid * 2 + 1) * 16 + srow) * 512 + scol;
  unsigned short* lA0 = &As[(wid * 2 + 0) * 512];
  unsigned short* lA1 = &As[(wid * 2 + 1) * 512];
  unsigned short* lB0 = &Bs[(wid * 2 + 0) * 512];
  unsigned short* lB1 = &Bs[(wid * 2 + 1) * 512];

  f32x4 acc[4][4];
  #pragma unroll
  for (int mi = 0; mi < 4; ++mi)
    #pragma unroll
    for (int ni = 0; ni < 4; ++ni)
      acc[mi][ni] = (f32x4){0.f, 0.f, 0.f, 0.f};

  for (int k0 = 0; k0 < 512; k0 += 32) {
    GLD16(gA0 + k0, lA0);
    GLD16(gA1 + k0, lA1);
    GLD16(gB0 + k0, lB0);
    GLD16(gB1 + k0, lB1);
    __syncthreads();
    bf16x8 af[4], bfr[4];
    #pragma unroll
    for (int mi = 0; mi < 4; ++mi)
      af[mi] = *(const bf16x8*)&As[(wr + mi * 16 + lr) * 32 + lk];
    #pragma unroll
    for (int ni = 0; ni < 4; ++ni)
      bfr[ni] = *(const bf16x8*)&Bs[(wc + ni * 16 + lr) * 32 + lk];
    #pragma unroll
    for (int mi = 0; mi < 4; ++mi)
      #pragma unroll
      for (int ni = 0; ni < 4; ++ni)
        acc[mi][ni] = MFMA16(af[mi], bfr[ni], acc[mi][ni]);
    __syncthreads();
  }

  #pragma unroll
  for (int ni = 0; ni < 4; ++ni) {
    int col = c0 + wc + ni * 16 + lr;
    float bias = b_out[col];
    #pragma unroll
    for (int mi = 0; mi < 4; ++mi)
      #pragma unroll
      for (int reg = 0; reg < 4; ++reg) {
        int row = r0 + wr + mi * 16 + (lane >> 4) * 4 + reg;
        out[(size_t)row * 512 + col] = acc[mi][ni][reg] + bias;
      }
  }
}

// ---------------------------------------------------------------------------
extern "C" void kernel_launch(void* const* d_in, const int* in_sizes, int n_in,
                              void* d_out, int out_size, void* d_ws, size_t ws_size,
                              hipStream_t stream) {
  const float* img       = (const float*)d_in[0];
  const float* tab       = (const float*)d_in[1];
  const float* w_qkv     = (const float*)d_in[2];
  const float* w_tab_qkv = (const float*)d_in[3];
  const float* w_out     = (const float*)d_in[4];
  const float* b_out     = (const float*)d_in[5];
  const float* ln_w      = (const float*)d_in[6];
  const float* ln_b      = (const float*)d_in[7];
  char* ws = (char*)d_ws;
  unsigned short* x_bf = (unsigned short*)(ws);             //  8 MiB
  unsigned short* wqt  = (unsigned short*)(ws + 8388608);   //  1.5 MiB
  unsigned short* wot  = (unsigned short*)(ws + 9961472);   //  0.5 MiB
  unsigned short* qh   = (unsigned short*)(ws + 10485760);  //  8 MiB
  unsigned short* kh   = (unsigned short*)(ws + 18874368);  //  8.25 MiB
  unsigned short* vt   = (unsigned short*)(ws + 27525120);  //  8.25 MiB
  unsigned short* ao   = (unsigned short*)(ws + 36175872);  //  8 MiB
  float*          t_ln = (float*)(ws + 44564480);           //  16 KiB
  float* out = (float*)d_out;

  hipLaunchKernelGGL(k_prep, dim3(256),  dim3(256), 0, stream, w_qkv, w_out, wqt, wot);
  hipLaunchKernelGGL(k_ln,   dim3(2050), dim3(256), 0, stream, img, tab, ln_w, ln_b, x_bf, t_ln);
  hipLaunchKernelGGL(k_tab,  dim3(8),    dim3(256), 0, stream, t_ln, w_tab_qkv, kh, vt);
  hipLaunchKernelGGL(k_qkv,  dim3(768),  dim3(256), 0, stream, x_bf, wqt, qh, kh, vt);
  hipLaunchKernelGGL(k_attn, dim3(1024), dim3(256), 0, stream, qh, kh, vt, ao);
  hipLaunchKernelGGL(k_out,  dim3(256),  dim3(256), 0, stream, ao, wot, b_out, out);
}

// Round 6
// 132.238 us; speedup vs baseline: 1.1231x; 1.1231x over previous
//
#include <hip/hip_runtime.h>

// ---------------------------------------------------------------------------
// Attention_43868795961547: LN -> QKV -> MHA(1025 keys) -> proj
// b=8, n=1024, dim=512, heads=8, dh=64. bf16 MFMA, f32 accum.
// Round 6: k_attn rebuilt as 8-wave block with LDS-staged K/V (KVBLK=64,
// double-buffered, XOR-swizzled via pre-swizzled gload_lds source).
// Keys padded to 1088 (17 tiles of 64).
// ---------------------------------------------------------------------------

typedef __attribute__((ext_vector_type(4))) float f32x4;
typedef __attribute__((ext_vector_type(16))) float f32x16;
typedef __attribute__((ext_vector_type(8))) short bf16x8;

#define MFMA16(a, b, c) __builtin_amdgcn_mfma_f32_16x16x32_bf16(a, b, c, 0, 0, 0)
#define MFMA32(a, b, c) __builtin_amdgcn_mfma_f32_32x32x16_bf16(a, b, c, 0, 0, 0)

#define GLD16(gsrc, ldst)                                                     \
  __builtin_amdgcn_global_load_lds(                                           \
      (const __attribute__((address_space(1))) void*)(gsrc),                  \
      (__attribute__((address_space(3))) void*)(ldst), 16, 0, 0)

#define KPAD 1088   // keys padded: 17 tiles of 64

// Q pre-scale: dots*0.125 in exp2-domain => fold 0.125*log2(e) into Q.
#define QSCALE 0.18033688011112042f

__device__ __forceinline__ unsigned short f2bf(float f) {
  union { float f; unsigned int u; } c; c.f = f;
  unsigned int u = c.u;
  u += 0x7fffu + ((u >> 16) & 1u);   // RNE
  return (unsigned short)(u >> 16);
}

__device__ __forceinline__ unsigned int cvtpk_bf16(float lo, float hi) {
  unsigned int r;
  asm("v_cvt_pk_bf16_f32 %0, %1, %2" : "=v"(r) : "v"(lo), "v"(hi));
  return r;
}

// ---- kernel 1: tiled transpose+convert weights to bf16 --------------------
__global__ __launch_bounds__(256) void k_prep(const float* __restrict__ w_qkv,
                                              const float* __restrict__ w_out,
                                              unsigned short* __restrict__ wqt,
                                              unsigned short* __restrict__ wot) {
  __shared__ unsigned short t[64][68];
  int blk = blockIdx.x, tid = threadIdx.x;
  const float* src;
  unsigned short* dst;
  int k0, n0, ldin;
  if (blk < 192) {
    int ti = blk / 24, tj = blk % 24;
    k0 = ti * 64; n0 = tj * 64; ldin = 1536;
    src = w_qkv; dst = wqt;
  } else {
    int g = blk - 192;
    int ti = g >> 3, tj = g & 7;
    k0 = ti * 64; n0 = tj * 64; ldin = 512;
    src = w_out; dst = wot;
  }
  int rr = tid >> 4, c4 = (tid & 15) * 4;
  #pragma unroll
  for (int i = 0; i < 4; ++i) {
    int r = i * 16 + rr;
    float4 v = *(const float4*)(src + (size_t)(k0 + r) * ldin + n0 + c4);
    t[c4 + 0][r] = f2bf(v.x);
    t[c4 + 1][r] = f2bf(v.y);
    t[c4 + 2][r] = f2bf(v.z);
    t[c4 + 3][r] = f2bf(v.w);
  }
  __syncthreads();
  #pragma unroll
  for (int i = 0; i < 4; ++i) {
    int r = i * 16 + rr;
    ushort4 w = *(const ushort4*)&t[r][c4];
    *(ushort4*)(dst + (size_t)(n0 + r) * 512 + k0 + c4) = w;
  }
}

// ---- kernel 2: LayerNorm (wave per row) -----------------------------------
__global__ __launch_bounds__(256) void k_ln(const float* __restrict__ img,
                                            const float* __restrict__ tab,
                                            const float* __restrict__ ln_w,
                                            const float* __restrict__ ln_b,
                                            unsigned short* __restrict__ x_bf,
                                            float* __restrict__ t_ln) {
  int wid = threadIdx.x >> 6, lane = threadIdx.x & 63;
  int row = blockIdx.x * 4 + wid;
  if (row >= 8200) return;
  const float* src = (row < 8192) ? img + (size_t)row * 512
                                  : tab + (size_t)(row - 8192) * 512;
  float4 v0 = *(const float4*)(src + lane * 8);
  float4 v1 = *(const float4*)(src + lane * 8 + 4);
  float x[8] = {v0.x, v0.y, v0.z, v0.w, v1.x, v1.y, v1.z, v1.w};
  float s = 0.f, sq = 0.f;
  #pragma unroll
  for (int j = 0; j < 8; ++j) { s += x[j]; sq += x[j] * x[j]; }
  #pragma unroll
  for (int off = 32; off >= 1; off >>= 1) {
    s  += __shfl_xor(s, off);
    sq += __shfl_xor(sq, off);
  }
  float mean = s * (1.0f / 512.0f);
  float var  = sq * (1.0f / 512.0f) - mean * mean;
  float rs = rsqrtf(var + 1e-5f);
  float4 w0 = *(const float4*)(ln_w + lane * 8);
  float4 w1 = *(const float4*)(ln_w + lane * 8 + 4);
  float4 b0 = *(const float4*)(ln_b + lane * 8);
  float4 b1 = *(const float4*)(ln_b + lane * 8 + 4);
  float w[8] = {w0.x, w0.y, w0.z, w0.w, w1.x, w1.y, w1.z, w1.w};
  float bb[8] = {b0.x, b0.y, b0.z, b0.w, b1.x, b1.y, b1.z, b1.w};
  float y[8];
  #pragma unroll
  for (int j = 0; j < 8; ++j) y[j] = (x[j] - mean) * rs * w[j] + bb[j];
  if (row < 8192) {
    bf16x8 o;
    #pragma unroll
    for (int j = 0; j < 8; ++j) o[j] = (short)f2bf(y[j]);
    *(bf16x8*)(x_bf + (size_t)row * 512 + lane * 8) = o;
  } else {
    float* dst = t_ln + (size_t)(row - 8192) * 512 + lane * 8;
    *(float4*)dst       = make_float4(y[0], y[1], y[2], y[3]);
    *(float4*)(dst + 4) = make_float4(y[4], y[5], y[6], y[7]);
  }
}

// ---- kernel 3: tab token k/v + zero pad rows ------------------------------
__global__ __launch_bounds__(256) void k_tab(const float* __restrict__ t_ln,
                                             const float* __restrict__ w_tab,
                                             unsigned short* __restrict__ kh,
                                             unsigned short* __restrict__ vt) {
  __shared__ float tl[512];
  int b = blockIdx.x, t = threadIdx.x;
  tl[t] = t_ln[b * 512 + t];
  tl[t + 256] = t_ln[b * 512 + t + 256];
  __syncthreads();
  float s[4] = {0.f, 0.f, 0.f, 0.f};
  for (int k = 0; k < 512; ++k) {
    float a = tl[k];
    #pragma unroll
    for (int i = 0; i < 4; ++i)
      s[i] += a * w_tab[(size_t)k * 1536 + 512 + i * 256 + t];
  }
  #pragma unroll
  for (int i = 0; i < 4; ++i) {
    int g = i * 256 + t;
    int part = g >> 9, hd = g & 511, h = hd >> 6, d = hd & 63;
    int bh = b * 8 + h;
    unsigned short hv = f2bf(s[i]);
    if (part == 0) kh[((size_t)bh * KPAD + 1024) * 64 + d] = hv;
    else           vt[((size_t)bh * 64 + d) * KPAD + 1024] = hv;
  }
  // zero pads: one (b,h) pair per block? block is per-b: zero all 8 heads
  for (int h = 0; h < 8; ++h) {
    int bh = b * 8 + h;
    for (int i = t; i < 63 * 64; i += 256) {
      int r = 1025 + (i >> 6), d = i & 63;
      kh[((size_t)bh * KPAD + r) * 64 + d] = 0;
    }
    for (int i = t; i < 64 * 63; i += 256) {
      int d = i / 63, c = 1025 + (i % 63);
      vt[((size_t)bh * 64 + d) * KPAD + c] = 0;
    }
  }
}

// ---- kernel 4: QKV GEMM, m97 structure ------------------------------------
__global__ __launch_bounds__(256) void k_qkv(const unsigned short* __restrict__ x_bf,
                                             const unsigned short* __restrict__ wqt,
                                             unsigned short* __restrict__ qh,
                                             unsigned short* __restrict__ kh,
                                             unsigned short* __restrict__ vt) {
  __shared__ unsigned short As[128 * 32];
  __shared__ unsigned short Bs[128 * 32];
  int tid = threadIdx.x;
  int wid = tid >> 6, lane = tid & 63;
  int bm = blockIdx.x & 63, bn = blockIdx.x >> 6;   // 64 x 12
  int r0 = bm * 128, c0 = bn * 128;
  int lr = lane & 15, lk = (lane >> 4) * 8;
  int wr = (wid >> 1) * 64, wc = (wid & 1) * 64;
  int srow = lane >> 2, scol = (lane & 3) * 8;
  const unsigned short* gA0 = x_bf + (size_t)(r0 + (wid * 2 + 0) * 16 + srow) * 512 + scol;
  const unsigned short* gA1 = x_bf + (size_t)(r0 + (wid * 2 + 1) * 16 + srow) * 512 + scol;
  const unsigned short* gB0 = wqt  + (size_t)(c0 + (wid * 2 + 0) * 16 + srow) * 512 + scol;
  const unsigned short* gB1 = wqt  + (size_t)(c0 + (wid * 2 + 1) * 16 + srow) * 512 + scol;
  unsigned short* lA0 = &As[(wid * 2 + 0) * 512];
  unsigned short* lA1 = &As[(wid * 2 + 1) * 512];
  unsigned short* lB0 = &Bs[(wid * 2 + 0) * 512];
  unsigned short* lB1 = &Bs[(wid * 2 + 1) * 512];

  f32x4 acc[4][4];
  #pragma unroll
  for (int mi = 0; mi < 4; ++mi)
    #pragma unroll
    for (int ni = 0; ni < 4; ++ni)
      acc[mi][ni] = (f32x4){0.f, 0.f, 0.f, 0.f};

  for (int k0 = 0; k0 < 512; k0 += 32) {
    GLD16(gA0 + k0, lA0);
    GLD16(gA1 + k0, lA1);
    GLD16(gB0 + k0, lB0);
    GLD16(gB1 + k0, lB1);
    __syncthreads();
    bf16x8 af[4], bfr[4];
    #pragma unroll
    for (int mi = 0; mi < 4; ++mi)
      af[mi] = *(const bf16x8*)&As[(wr + mi * 16 + lr) * 32 + lk];
    #pragma unroll
    for (int ni = 0; ni < 4; ++ni)
      bfr[ni] = *(const bf16x8*)&Bs[(wc + ni * 16 + lr) * 32 + lk];
    #pragma unroll
    for (int mi = 0; mi < 4; ++mi)
      #pragma unroll
      for (int ni = 0; ni < 4; ++ni)
        acc[mi][ni] = MFMA16(af[mi], bfr[ni], acc[mi][ni]);
    __syncthreads();
  }

  #pragma unroll
  for (int ni = 0; ni < 4; ++ni) {
    int col0 = c0 + wc + ni * 16;
    int which = col0 >> 9;
    int hh = (col0 & 511) >> 6;
    int d = (col0 & 63) + lr;
    #pragma unroll
    for (int mi = 0; mi < 4; ++mi)
      #pragma unroll
      for (int reg = 0; reg < 4; ++reg) {
        int row = r0 + wr + mi * 16 + (lane >> 4) * 4 + reg;
        int b = row >> 10, n = row & 1023;
        int bh = b * 8 + hh;
        float v = acc[mi][ni][reg];
        if (which == 0) {
          qh[((size_t)bh * 1024 + n) * 64 + d] = f2bf(v * QSCALE);
        } else if (which == 1) {
          kh[((size_t)bh * KPAD + n) * 64 + d] = f2bf(v);
        } else {
          vt[((size_t)bh * 64 + d) * KPAD + n] = f2bf(v);
        }
      }
  }
}

// ---- kernel 5: flash attention, 8-wave block + LDS-staged K/V -------------
// 256 blocks x 512 thr. Block = (bh, quarter of q). Wave = 32 q-rows.
// K/V tiles of 64 keys staged to LDS (double-buffered) via global_load_lds,
// XOR-swizzled (chunk ^= row&7, 16B chunks in 128B rows) via pre-swizzled
// global source + swizzled ds_read. Swapped QK^T, in-reg softmax, defer-max.
__global__ __launch_bounds__(512, 4) void k_attn(const unsigned short* __restrict__ qh,
                                                 const unsigned short* __restrict__ kh,
                                                 const unsigned short* __restrict__ vt,
                                                 unsigned short* __restrict__ ao) {
  __shared__ __align__(16) unsigned short Ks[2][4096];  // [64 key][64 d] swz
  __shared__ __align__(16) unsigned short Vs[2][4096];  // [64 d][64 key] swz
  int tid = threadIdx.x;
  int wid = tid >> 6, lane = tid & 63;
  int bid = blockIdx.x;
  int swz = ((bid & 7) << 5) | (bid >> 3);   // bijective; 8 bh per XCD
  int bh = swz >> 2;
  int q0 = (swz & 3) * 256 + wid * 32;
  int lq = lane & 31, half = lane >> 5;

  const unsigned short* Q  = qh + (size_t)bh * 1024 * 64;
  const unsigned short* Kg = kh + (size_t)bh * KPAD * 64;
  const unsigned short* Vg = vt + (size_t)bh * 64 * KPAD;

  // staging: thread stages 16B at LDS byte x = tid*16; row = x>>7 = tid>>3,
  // chunk = (tid&7) ^ (row&7) (involution).
  int xr = tid >> 3;
  int xc = (tid & 7) ^ (xr & 7);
  const unsigned short* kg_src = Kg + xr * 64 + xc * 8;
  const unsigned short* vg_src = Vg + (size_t)xr * KPAD + xc * 8;
  unsigned short* kdstA = &Ks[0][wid * 512];
  unsigned short* kdstB = &Ks[1][wid * 512];
  unsigned short* vdstA = &Vs[0][wid * 512];
  unsigned short* vdstB = &Vs[1][wid * 512];

  // Q fragments (B-operand)
  bf16x8 qf[4];
  const unsigned short* qlane = Q + (size_t)(q0 + lq) * 64 + half * 8;
  #pragma unroll
  for (int dt = 0; dt < 4; ++dt)
    qf[dt] = *(const bf16x8*)(qlane + dt * 16);

  f32x16 o0 = (f32x16)(0.0f), o1 = (f32x16)(0.0f);
  float m = -1e30f, lsum = 0.f;

  // prologue: stage tile 0 into buffer 0
  GLD16(kg_src, kdstA);
  GLD16(vg_src, vdstA);
  __syncthreads();

  for (int kt = 0; kt < 17; ++kt) {
    int cur = kt & 1;
    if (kt < 16) {
      GLD16(kg_src + (kt + 1) * 4096, cur ? kdstA : kdstB);
      GLD16(vg_src + (kt + 1) * 64,   cur ? vdstA : vdstB);
    }
    const unsigned short* Kb = Ks[cur];
    const unsigned short* Vb = Vs[cur];
    #pragma unroll
    for (int sub = 0; sub < 2; ++sub) {
      // K fragments from LDS (swizzled)
      int krow = sub * 32 + lq;
      bf16x8 kf[4];
      #pragma unroll
      for (int dt = 0; dt < 4; ++dt) {
        int ch = (half + dt * 2) ^ (krow & 7);
        kf[dt] = *(const bf16x8*)&Kb[krow * 64 + ch * 8];
      }
      f32x16 s = (f32x16)(0.0f);
      __builtin_amdgcn_s_setprio(1);
      #pragma unroll
      for (int dt = 0; dt < 4; ++dt)
        s = MFMA32(kf[dt], qf[dt], s);
      __builtin_amdgcn_s_setprio(0);
      // mask padded keys (tile 16: sub0 only key 1024 valid; sub1 none)
      if (kt == 16) {
        if (sub == 0) {
          #pragma unroll
          for (int reg = 0; reg < 16; ++reg) {
            if (reg == 0) { if (half) s[0] = -1e30f; }
            else s[reg] = -1e30f;
          }
        } else {
          #pragma unroll
          for (int reg = 0; reg < 16; ++reg) s[reg] = -1e30f;
        }
      }
      // row max
      float pmax = s[0];
      #pragma unroll
      for (int reg = 1; reg < 16; ++reg) pmax = fmaxf(pmax, s[reg]);
      pmax = fmaxf(pmax, __shfl_xor(pmax, 32));
      // defer-max rescale
      if (!__all(pmax <= m + 8.0f)) {
        float mnew = fmaxf(m, pmax);
        float al = __builtin_amdgcn_exp2f(m - mnew);
        lsum *= al;
        #pragma unroll
        for (int reg = 0; reg < 16; ++reg) { o0[reg] *= al; o1[reg] *= al; }
        m = mnew;
      }
      float p[16];
      float ls = 0.f;
      #pragma unroll
      for (int reg = 0; reg < 16; ++reg) {
        p[reg] = __builtin_amdgcn_exp2f(s[reg] - m);
        ls += p[reg];
      }
      lsum += ls;
      // pack P -> bf16 B-fragments
      unsigned int c0x0 = cvtpk_bf16(p[0],  p[1]);
      unsigned int c0x1 = cvtpk_bf16(p[2],  p[3]);
      unsigned int c0y0 = cvtpk_bf16(p[4],  p[5]);
      unsigned int c0y1 = cvtpk_bf16(p[6],  p[7]);
      unsigned int c1x0 = cvtpk_bf16(p[8],  p[9]);
      unsigned int c1x1 = cvtpk_bf16(p[10], p[11]);
      unsigned int c1y0 = cvtpk_bf16(p[12], p[13]);
      unsigned int c1y1 = cvtpk_bf16(p[14], p[15]);
      asm volatile("v_permlane32_swap_b32 %0, %1" : "+v"(c0x0), "+v"(c0y0));
      asm volatile("v_permlane32_swap_b32 %0, %1" : "+v"(c0x1), "+v"(c0y1));
      asm volatile("v_permlane32_swap_b32 %0, %1" : "+v"(c1x0), "+v"(c1y0));
      asm volatile("v_permlane32_swap_b32 %0, %1" : "+v"(c1x1), "+v"(c1y1));
      union { unsigned int w[4]; bf16x8 v; } f0, f1;
      f0.w[0] = c0x0; f0.w[1] = c0x1; f0.w[2] = c0y0; f0.w[3] = c0y1;
      f1.w[0] = c1x0; f1.w[1] = c1x1; f1.w[2] = c1y0; f1.w[3] = c1y1;
      // V fragments from LDS (swizzled): rows d=lq, d=lq+32
      int vr0 = lq, vr1 = lq + 32;
      int cb = sub * 4 + half;
      bf16x8 vf0 = *(const bf16x8*)&Vb[vr0 * 64 + ((cb + 0) ^ (vr0 & 7)) * 8];
      bf16x8 vf1 = *(const bf16x8*)&Vb[vr0 * 64 + ((cb + 2) ^ (vr0 & 7)) * 8];
      bf16x8 vf2 = *(const bf16x8*)&Vb[vr1 * 64 + ((cb + 0) ^ (vr1 & 7)) * 8];
      bf16x8 vf3 = *(const bf16x8*)&Vb[vr1 * 64 + ((cb + 2) ^ (vr1 & 7)) * 8];
      __builtin_amdgcn_s_setprio(1);
      o0 = MFMA32(vf0, f0.v, o0);
      o0 = MFMA32(vf1, f1.v, o0);
      o1 = MFMA32(vf2, f0.v, o1);
      o1 = MFMA32(vf3, f1.v, o1);
      __builtin_amdgcn_s_setprio(0);
    }
    __syncthreads();
  }
  // epilogue: combine half-sums, normalize, store
  lsum += __shfl_xor(lsum, 32);
  float rl = 1.0f / lsum;
  int b = bh >> 3, h = bh & 7;
  unsigned short* aorow = ao + ((size_t)(b * 1024 + q0 + lq)) * 512 + h * 64;
  #pragma unroll
  for (int dt2 = 0; dt2 < 2; ++dt2) {
    #pragma unroll
    for (int g = 0; g < 4; ++g) {
      ushort4 pk;
      float v0 = (dt2 ? o1[4 * g + 0] : o0[4 * g + 0]) * rl;
      float v1 = (dt2 ? o1[4 * g + 1] : o0[4 * g + 1]) * rl;
      float v2 = (dt2 ? o1[4 * g + 2] : o0[4 * g + 2]) * rl;
      float v3 = (dt2 ? o1[4 * g + 3] : o0[4 * g + 3]) * rl;
      pk.x = f2bf(v0); pk.y = f2bf(v1); pk.z = f2bf(v2); pk.w = f2bf(v3);
      *(ushort4*)(aorow + dt2 * 32 + 8 * g + 4 * half) = pk;
    }
  }
}

// ---- kernel 6: output GEMM + bias, m97 structure --------------------------
__global__ __launch_bounds__(256) void k_out(const unsigned short* __restrict__ ao,
                                             const unsigned short* __restrict__ wot,
                                             const float* __restrict__ b_out,
                                             float* __restrict__ out) {
  __shared__ unsigned short As[128 * 32];
  __shared__ unsigned short Bs[128 * 32];
  int tid = threadIdx.x;
  int wid = tid >> 6, lane = tid & 63;
  int bm = blockIdx.x & 63, bn = blockIdx.x >> 6;   // 64 x 4
  int r0 = bm * 128, c0 = bn * 128;
  int lr = lane & 15, lk = (lane >> 4) * 8;
  int wr = (wid >> 1) * 64, wc = (wid & 1) * 64;
  int srow = lane >> 2, scol = (lane & 3) * 8;
  const unsigned short* gA0 = ao  + (size_t)(r0 + (wid * 2 + 0) * 16 + srow) * 512 + scol;
  const unsigned short* gA1 = ao  + (size_t)(r0 + (wid * 2 + 1) * 16 + srow) * 512 + scol;
  const unsigned short* gB0 = wot + (size_t)(c0 + (wid * 2 + 0) * 16 + srow) * 512 + scol;
  const unsigned short* gB1 = wot + (size_t)(c0 + (wid * 2 + 1) * 16 + srow) * 512 + scol;
  unsigned short* lA0 = &As[(wid * 2 + 0) * 512];
  unsigned short* lA1 = &As[(wid * 2 + 1) * 512];
  unsigned short* lB0 = &Bs[(wid * 2 + 0) * 512];
  unsigned short* lB1 = &Bs[(wid * 2 + 1) * 512];

  f32x4 acc[4][4];
  #pragma unroll
  for (int mi = 0; mi < 4; ++mi)
    #pragma unroll
    for (int ni = 0; ni < 4; ++ni)
      acc[mi][ni] = (f32x4){0.f, 0.f, 0.f, 0.f};

  for (int k0 = 0; k0 < 512; k0 += 32) {
    GLD16(gA0 + k0, lA0);
    GLD16(gA1 + k0, lA1);
    GLD16(gB0 + k0, lB0);
    GLD16(gB1 + k0, lB1);
    __syncthreads();
    bf16x8 af[4], bfr[4];
    #pragma unroll
    for (int mi = 0; mi < 4; ++mi)
      af[mi] = *(const bf16x8*)&As[(wr + mi * 16 + lr) * 32 + lk];
    #pragma unroll
    for (int ni = 0; ni < 4; ++ni)
      bfr[ni] = *(const bf16x8*)&Bs[(wc + ni * 16 + lr) * 32 + lk];
    #pragma unroll
    for (int mi = 0; mi < 4; ++mi)
      #pragma unroll
      for (int ni = 0; ni < 4; ++ni)
        acc[mi][ni] = MFMA16(af[mi], bfr[ni], acc[mi][ni]);
    __syncthreads();
  }

  #pragma unroll
  for (int ni = 0; ni < 4; ++ni) {
    int col = c0 + wc + ni * 16 + lr;
    float bias = b_out[col];
    #pragma unroll
    for (int mi = 0; mi < 4; ++mi)
      #pragma unroll
      for (int reg = 0; reg < 4; ++reg) {
        int row = r0 + wr + mi * 16 + (lane >> 4) * 4 + reg;
        out[(size_t)row * 512 + col] = acc[mi][ni][reg] + bias;
      }
  }
}

// ---------------------------------------------------------------------------
extern "C" void kernel_launch(void* const* d_in, const int* in_sizes, int n_in,
                              void* d_out, int out_size, void* d_ws, size_t ws_size,
                              hipStream_t stream) {
  const float* img       = (const float*)d_in[0];
  const float* tab       = (const float*)d_in[1];
  const float* w_qkv     = (const float*)d_in[2];
  const float* w_tab_qkv = (const float*)d_in[3];
  const float* w_out     = (const float*)d_in[4];
  const float* b_out     = (const float*)d_in[5];
  const float* ln_w      = (const float*)d_in[6];
  const float* ln_b      = (const float*)d_in[7];
  char* ws = (char*)d_ws;
  unsigned short* x_bf = (unsigned short*)(ws);             //  8 MiB
  unsigned short* wqt  = (unsigned short*)(ws + 8388608);   //  1.5 MiB
  unsigned short* wot  = (unsigned short*)(ws + 9961472);   //  0.5 MiB
  unsigned short* qh   = (unsigned short*)(ws + 10485760);  //  8 MiB
  unsigned short* kh   = (unsigned short*)(ws + 18874368);  //  8.5 MiB (KPAD)
  unsigned short* vt   = (unsigned short*)(ws + 27787264);  //  8.5 MiB (KPAD)
  unsigned short* ao   = (unsigned short*)(ws + 36700160);  //  8 MiB
  float*          t_ln = (float*)(ws + 45088768);           //  16 KiB
  float* out = (float*)d_out;

  hipLaunchKernelGGL(k_prep, dim3(256),  dim3(256), 0, stream, w_qkv, w_out, wqt, wot);
  hipLaunchKernelGGL(k_ln,   dim3(2050), dim3(256), 0, stream, img, tab, ln_w, ln_b, x_bf, t_ln);
  hipLaunchKernelGGL(k_tab,  dim3(8),    dim3(256), 0, stream, t_ln, w_tab_qkv, kh, vt);
  hipLaunchKernelGGL(k_qkv,  dim3(768),  dim3(256), 0, stream, x_bf, wqt, qh, kh, vt);
  hipLaunchKernelGGL(k_attn, dim3(256),  dim3(512), 0, stream, qh, kh, vt, ao);
  hipLaunchKernelGGL(k_out,  dim3(256),  dim3(256), 0, stream, ao, wot, b_out, out);
}

// Round 8
// 97.691 us; speedup vs baseline: 1.5202x; 1.3536x over previous
//
#include <hip/hip_runtime.h>

// ---------------------------------------------------------------------------
// Attention_43868795961547: LN -> QKV -> MHA(1025 keys) -> proj
// b=8, n=1024, dim=512, heads=8, dh=64. bf16 MFMA, f32 accum.
// Round 8: k_tab parallel (128 blocks) WITH integrated race-free pad zeroing
// (rows/cols 1024..1087 zeroed by the same block that writes the tab token,
// ordered by the block's __syncthreads). Never read ws bytes not written
// this call. k_attn/k_qkv/k_out as round 6 (passing).
// ---------------------------------------------------------------------------

typedef __attribute__((ext_vector_type(4))) float f32x4;
typedef __attribute__((ext_vector_type(16))) float f32x16;
typedef __attribute__((ext_vector_type(8))) short bf16x8;
typedef __attribute__((ext_vector_type(8))) unsigned short u16x8;

#define MFMA16(a, b, c) __builtin_amdgcn_mfma_f32_16x16x32_bf16(a, b, c, 0, 0, 0)
#define MFMA32(a, b, c) __builtin_amdgcn_mfma_f32_32x32x16_bf16(a, b, c, 0, 0, 0)

#define GLD16(gsrc, ldst)                                                     \
  __builtin_amdgcn_global_load_lds(                                           \
      (const __attribute__((address_space(1))) void*)(gsrc),                  \
      (__attribute__((address_space(3))) void*)(ldst), 16, 0, 0)

#define KPAD 1088   // keys padded: 17 tiles of 64

// Q pre-scale: dots*0.125 in exp2-domain => fold 0.125*log2(e) into Q.
#define QSCALE 0.18033688011112042f

__device__ __forceinline__ unsigned short f2bf(float f) {
  union { float f; unsigned int u; } c; c.f = f;
  unsigned int u = c.u;
  u += 0x7fffu + ((u >> 16) & 1u);   // RNE
  return (unsigned short)(u >> 16);
}

__device__ __forceinline__ unsigned int cvtpk_bf16(float lo, float hi) {
  unsigned int r;
  asm("v_cvt_pk_bf16_f32 %0, %1, %2" : "=v"(r) : "v"(lo), "v"(hi));
  return r;
}

// ---- kernel 1: tiled transpose+convert weights to bf16 --------------------
__global__ __launch_bounds__(256) void k_prep(const float* __restrict__ w_qkv,
                                              const float* __restrict__ w_out,
                                              unsigned short* __restrict__ wqt,
                                              unsigned short* __restrict__ wot) {
  __shared__ unsigned short t[64][68];
  int blk = blockIdx.x, tid = threadIdx.x;
  const float* src;
  unsigned short* dst;
  int k0, n0, ldin;
  if (blk < 192) {
    int ti = blk / 24, tj = blk % 24;
    k0 = ti * 64; n0 = tj * 64; ldin = 1536;
    src = w_qkv; dst = wqt;
  } else {
    int g = blk - 192;
    int ti = g >> 3, tj = g & 7;
    k0 = ti * 64; n0 = tj * 64; ldin = 512;
    src = w_out; dst = wot;
  }
  int rr = tid >> 4, c4 = (tid & 15) * 4;
  #pragma unroll
  for (int i = 0; i < 4; ++i) {
    int r = i * 16 + rr;
    float4 v = *(const float4*)(src + (size_t)(k0 + r) * ldin + n0 + c4);
    t[c4 + 0][r] = f2bf(v.x);
    t[c4 + 1][r] = f2bf(v.y);
    t[c4 + 2][r] = f2bf(v.z);
    t[c4 + 3][r] = f2bf(v.w);
  }
  __syncthreads();
  #pragma unroll
  for (int i = 0; i < 4; ++i) {
    int r = i * 16 + rr;
    ushort4 w = *(const ushort4*)&t[r][c4];
    *(ushort4*)(dst + (size_t)(n0 + r) * 512 + k0 + c4) = w;
  }
}

// ---- kernel 2: LayerNorm (wave per row) -----------------------------------
__global__ __launch_bounds__(256) void k_ln(const float* __restrict__ img,
                                            const float* __restrict__ tab,
                                            const float* __restrict__ ln_w,
                                            const float* __restrict__ ln_b,
                                            unsigned short* __restrict__ x_bf,
                                            float* __restrict__ t_ln) {
  int wid = threadIdx.x >> 6, lane = threadIdx.x & 63;
  int row = blockIdx.x * 4 + wid;
  if (row >= 8200) return;
  const float* src = (row < 8192) ? img + (size_t)row * 512
                                  : tab + (size_t)(row - 8192) * 512;
  float4 v0 = *(const float4*)(src + lane * 8);
  float4 v1 = *(const float4*)(src + lane * 8 + 4);
  float x[8] = {v0.x, v0.y, v0.z, v0.w, v1.x, v1.y, v1.z, v1.w};
  float s = 0.f, sq = 0.f;
  #pragma unroll
  for (int j = 0; j < 8; ++j) { s += x[j]; sq += x[j] * x[j]; }
  #pragma unroll
  for (int off = 32; off >= 1; off >>= 1) {
    s  += __shfl_xor(s, off);
    sq += __shfl_xor(sq, off);
  }
  float mean = s * (1.0f / 512.0f);
  float var  = sq * (1.0f / 512.0f) - mean * mean;
  float rs = rsqrtf(var + 1e-5f);
  float4 w0 = *(const float4*)(ln_w + lane * 8);
  float4 w1 = *(const float4*)(ln_w + lane * 8 + 4);
  float4 b0 = *(const float4*)(ln_b + lane * 8);
  float4 b1 = *(const float4*)(ln_b + lane * 8 + 4);
  float w[8] = {w0.x, w0.y, w0.z, w0.w, w1.x, w1.y, w1.z, w1.w};
  float bb[8] = {b0.x, b0.y, b0.z, b0.w, b1.x, b1.y, b1.z, b1.w};
  float y[8];
  #pragma unroll
  for (int j = 0; j < 8; ++j) y[j] = (x[j] - mean) * rs * w[j] + bb[j];
  if (row < 8192) {
    bf16x8 o;
    #pragma unroll
    for (int j = 0; j < 8; ++j) o[j] = (short)f2bf(y[j]);
    *(bf16x8*)(x_bf + (size_t)row * 512 + lane * 8) = o;
  } else {
    float* dst = t_ln + (size_t)(row - 8192) * 512 + lane * 8;
    *(float4*)dst       = make_float4(y[0], y[1], y[2], y[3]);
    *(float4*)(dst + 4) = make_float4(y[4], y[5], y[6], y[7]);
  }
}

// ---- kernel 3: tab token k/v + pad zeroing (128 blocks) -------------------
// Block (b, chunk): chunk<8 -> k-part head h=chunk; chunk>=8 -> v-part head
// h=chunk-8. Same block zeroes its head's pad region (keys 1024..1087) BEFORE
// the __syncthreads, then writes the tab token at key 1024 after it.
__global__ __launch_bounds__(256) void k_tab(const float* __restrict__ t_ln,
                                             const float* __restrict__ w_tab,
                                             unsigned short* __restrict__ kh,
                                             unsigned short* __restrict__ vt) {
  __shared__ float red[4][64];
  int blk = blockIdx.x;            // 128 blocks
  int b = blk >> 4, chunk = blk & 15;
  int t = threadIdx.x;
  int cl = t & 63;                  // col within chunk
  int ks = t >> 6;                  // K-slice (one per wave)
  int col = chunk * 64 + cl;        // 0..1023 over [k | v] x [h] x [d]

  // ---- pad zeroing for this block's (bh) region ----
  {
    int h = chunk & 7;
    int bh = b * 8 + h;
    u16x8 z = (u16x8)(0);
    if (chunk < 8) {
      // K rows 1024..1087: contiguous 4096 elems, 512 x ushort8
      unsigned short* base = kh + ((size_t)bh * KPAD + 1024) * 64;
      #pragma unroll
      for (int i = 0; i < 2; ++i)
        *(u16x8*)(base + (t + i * 256) * 8) = z;
    } else {
      // V cols 1024..1087 for d=0..63: 64 rows x 8 ushort8-chunks
      #pragma unroll
      for (int i = 0; i < 2; ++i) {
        int idx = t + i * 256;             // 0..511
        int d = idx >> 3, ch = idx & 7;
        *(u16x8*)(vt + ((size_t)bh * 64 + d) * KPAD + 1024 + ch * 8) = z;
      }
    }
  }

  // ---- tab GEMV (K-split across 4 waves) ----
  const float* tl = t_ln + b * 512;
  const float* wp = w_tab + 512 + col + (size_t)(ks * 128) * 1536;
  float s = 0.f;
  #pragma unroll 8
  for (int k = 0; k < 128; ++k)
    s += tl[ks * 128 + k] * wp[(size_t)k * 1536];
  red[ks][cl] = s;
  __syncthreads();
  if (ks == 0) {
    float v = red[0][cl] + red[1][cl] + red[2][cl] + red[3][cl];
    int part = col >> 9, hd = col & 511, h = hd >> 6, d = hd & 63;
    int bh = b * 8 + h;
    unsigned short hv = f2bf(v);
    if (part == 0) kh[((size_t)bh * KPAD + 1024) * 64 + d] = hv;
    else           vt[((size_t)bh * 64 + d) * KPAD + 1024] = hv;
  }
}

// ---- kernel 4: QKV GEMM, m97 structure ------------------------------------
__global__ __launch_bounds__(256) void k_qkv(const unsigned short* __restrict__ x_bf,
                                             const unsigned short* __restrict__ wqt,
                                             unsigned short* __restrict__ qh,
                                             unsigned short* __restrict__ kh,
                                             unsigned short* __restrict__ vt) {
  __shared__ unsigned short As[128 * 32];
  __shared__ unsigned short Bs[128 * 32];
  int tid = threadIdx.x;
  int wid = tid >> 6, lane = tid & 63;
  int bm = blockIdx.x & 63, bn = blockIdx.x >> 6;   // 64 x 12
  int r0 = bm * 128, c0 = bn * 128;
  int lr = lane & 15, lk = (lane >> 4) * 8;
  int wr = (wid >> 1) * 64, wc = (wid & 1) * 64;
  int srow = lane >> 2, scol = (lane & 3) * 8;
  const unsigned short* gA0 = x_bf + (size_t)(r0 + (wid * 2 + 0) * 16 + srow) * 512 + scol;
  const unsigned short* gA1 = x_bf + (size_t)(r0 + (wid * 2 + 1) * 16 + srow) * 512 + scol;
  const unsigned short* gB0 = wqt  + (size_t)(c0 + (wid * 2 + 0) * 16 + srow) * 512 + scol;
  const unsigned short* gB1 = wqt  + (size_t)(c0 + (wid * 2 + 1) * 16 + srow) * 512 + scol;
  unsigned short* lA0 = &As[(wid * 2 + 0) * 512];
  unsigned short* lA1 = &As[(wid * 2 + 1) * 512];
  unsigned short* lB0 = &Bs[(wid * 2 + 0) * 512];
  unsigned short* lB1 = &Bs[(wid * 2 + 1) * 512];

  f32x4 acc[4][4];
  #pragma unroll
  for (int mi = 0; mi < 4; ++mi)
    #pragma unroll
    for (int ni = 0; ni < 4; ++ni)
      acc[mi][ni] = (f32x4){0.f, 0.f, 0.f, 0.f};

  for (int k0 = 0; k0 < 512; k0 += 32) {
    GLD16(gA0 + k0, lA0);
    GLD16(gA1 + k0, lA1);
    GLD16(gB0 + k0, lB0);
    GLD16(gB1 + k0, lB1);
    __syncthreads();
    bf16x8 af[4], bfr[4];
    #pragma unroll
    for (int mi = 0; mi < 4; ++mi)
      af[mi] = *(const bf16x8*)&As[(wr + mi * 16 + lr) * 32 + lk];
    #pragma unroll
    for (int ni = 0; ni < 4; ++ni)
      bfr[ni] = *(const bf16x8*)&Bs[(wc + ni * 16 + lr) * 32 + lk];
    #pragma unroll
    for (int mi = 0; mi < 4; ++mi)
      #pragma unroll
      for (int ni = 0; ni < 4; ++ni)
        acc[mi][ni] = MFMA16(af[mi], bfr[ni], acc[mi][ni]);
    __syncthreads();
  }

  #pragma unroll
  for (int ni = 0; ni < 4; ++ni) {
    int col0 = c0 + wc + ni * 16;
    int which = col0 >> 9;
    int hh = (col0 & 511) >> 6;
    int d = (col0 & 63) + lr;
    #pragma unroll
    for (int mi = 0; mi < 4; ++mi)
      #pragma unroll
      for (int reg = 0; reg < 4; ++reg) {
        int row = r0 + wr + mi * 16 + (lane >> 4) * 4 + reg;
        int b = row >> 10, n = row & 1023;
        int bh = b * 8 + hh;
        float v = acc[mi][ni][reg];
        if (which == 0) {
          qh[((size_t)bh * 1024 + n) * 64 + d] = f2bf(v * QSCALE);
        } else if (which == 1) {
          kh[((size_t)bh * KPAD + n) * 64 + d] = f2bf(v);
        } else {
          vt[((size_t)bh * 64 + d) * KPAD + n] = f2bf(v);
        }
      }
  }
}

// ---- kernel 5: flash attention, 8-wave block + LDS-staged K/V -------------
__global__ __launch_bounds__(512, 4) void k_attn(const unsigned short* __restrict__ qh,
                                                 const unsigned short* __restrict__ kh,
                                                 const unsigned short* __restrict__ vt,
                                                 unsigned short* __restrict__ ao) {
  __shared__ __align__(16) unsigned short Ks[2][4096];  // [64 key][64 d] swz
  __shared__ __align__(16) unsigned short Vs[2][4096];  // [64 d][64 key] swz
  int tid = threadIdx.x;
  int wid = tid >> 6, lane = tid & 63;
  int bid = blockIdx.x;
  int swz = ((bid & 7) << 5) | (bid >> 3);   // bijective; 8 bh per XCD
  int bh = swz >> 2;
  int q0 = (swz & 3) * 256 + wid * 32;
  int lq = lane & 31, half = lane >> 5;

  const unsigned short* Q  = qh + (size_t)bh * 1024 * 64;
  const unsigned short* Kg = kh + (size_t)bh * KPAD * 64;
  const unsigned short* Vg = vt + (size_t)bh * 64 * KPAD;

  int xr = tid >> 3;
  int xc = (tid & 7) ^ (xr & 7);
  const unsigned short* kg_src = Kg + xr * 64 + xc * 8;
  const unsigned short* vg_src = Vg + (size_t)xr * KPAD + xc * 8;
  unsigned short* kdstA = &Ks[0][wid * 512];
  unsigned short* kdstB = &Ks[1][wid * 512];
  unsigned short* vdstA = &Vs[0][wid * 512];
  unsigned short* vdstB = &Vs[1][wid * 512];

  bf16x8 qf[4];
  const unsigned short* qlane = Q + (size_t)(q0 + lq) * 64 + half * 8;
  #pragma unroll
  for (int dt = 0; dt < 4; ++dt)
    qf[dt] = *(const bf16x8*)(qlane + dt * 16);

  f32x16 o0 = (f32x16)(0.0f), o1 = (f32x16)(0.0f);
  float m = -1e30f, lsum = 0.f;

  GLD16(kg_src, kdstA);
  GLD16(vg_src, vdstA);
  __syncthreads();

  for (int kt = 0; kt < 17; ++kt) {
    int cur = kt & 1;
    if (kt < 16) {
      GLD16(kg_src + (kt + 1) * 4096, cur ? kdstA : kdstB);
      GLD16(vg_src + (kt + 1) * 64,   cur ? vdstA : vdstB);
    }
    const unsigned short* Kb = Ks[cur];
    const unsigned short* Vb = Vs[cur];
    #pragma unroll
    for (int sub = 0; sub < 2; ++sub) {
      int krow = sub * 32 + lq;
      bf16x8 kf[4];
      #pragma unroll
      for (int dt = 0; dt < 4; ++dt) {
        int ch = (half + dt * 2) ^ (krow & 7);
        kf[dt] = *(const bf16x8*)&Kb[krow * 64 + ch * 8];
      }
      f32x16 s = (f32x16)(0.0f);
      __builtin_amdgcn_s_setprio(1);
      #pragma unroll
      for (int dt = 0; dt < 4; ++dt)
        s = MFMA32(kf[dt], qf[dt], s);
      __builtin_amdgcn_s_setprio(0);
      if (kt == 16) {
        if (sub == 0) {
          #pragma unroll
          for (int reg = 0; reg < 16; ++reg) {
            if (reg == 0) { if (half) s[0] = -1e30f; }
            else s[reg] = -1e30f;
          }
        } else {
          #pragma unroll
          for (int reg = 0; reg < 16; ++reg) s[reg] = -1e30f;
        }
      }
      float pmax = s[0];
      #pragma unroll
      for (int reg = 1; reg < 16; ++reg) pmax = fmaxf(pmax, s[reg]);
      pmax = fmaxf(pmax, __shfl_xor(pmax, 32));
      if (!__all(pmax <= m + 8.0f)) {
        float mnew = fmaxf(m, pmax);
        float al = __builtin_amdgcn_exp2f(m - mnew);
        lsum *= al;
        #pragma unroll
        for (int reg = 0; reg < 16; ++reg) { o0[reg] *= al; o1[reg] *= al; }
        m = mnew;
      }
      float p[16];
      float ls = 0.f;
      #pragma unroll
      for (int reg = 0; reg < 16; ++reg) {
        p[reg] = __builtin_amdgcn_exp2f(s[reg] - m);
        ls += p[reg];
      }
      lsum += ls;
      unsigned int c0x0 = cvtpk_bf16(p[0],  p[1]);
      unsigned int c0x1 = cvtpk_bf16(p[2],  p[3]);
      unsigned int c0y0 = cvtpk_bf16(p[4],  p[5]);
      unsigned int c0y1 = cvtpk_bf16(p[6],  p[7]);
      unsigned int c1x0 = cvtpk_bf16(p[8],  p[9]);
      unsigned int c1x1 = cvtpk_bf16(p[10], p[11]);
      unsigned int c1y0 = cvtpk_bf16(p[12], p[13]);
      unsigned int c1y1 = cvtpk_bf16(p[14], p[15]);
      asm volatile("v_permlane32_swap_b32 %0, %1" : "+v"(c0x0), "+v"(c0y0));
      asm volatile("v_permlane32_swap_b32 %0, %1" : "+v"(c0x1), "+v"(c0y1));
      asm volatile("v_permlane32_swap_b32 %0, %1" : "+v"(c1x0), "+v"(c1y0));
      asm volatile("v_permlane32_swap_b32 %0, %1" : "+v"(c1x1), "+v"(c1y1));
      union { unsigned int w[4]; bf16x8 v; } f0, f1;
      f0.w[0] = c0x0; f0.w[1] = c0x1; f0.w[2] = c0y0; f0.w[3] = c0y1;
      f1.w[0] = c1x0; f1.w[1] = c1x1; f1.w[2] = c1y0; f1.w[3] = c1y1;
      int vr0 = lq, vr1 = lq + 32;
      int cb = sub * 4 + half;
      bf16x8 vf0 = *(const bf16x8*)&Vb[vr0 * 64 + ((cb + 0) ^ (vr0 & 7)) * 8];
      bf16x8 vf1 = *(const bf16x8*)&Vb[vr0 * 64 + ((cb + 2) ^ (vr0 & 7)) * 8];
      bf16x8 vf2 = *(const bf16x8*)&Vb[vr1 * 64 + ((cb + 0) ^ (vr1 & 7)) * 8];
      bf16x8 vf3 = *(const bf16x8*)&Vb[vr1 * 64 + ((cb + 2) ^ (vr1 & 7)) * 8];
      __builtin_amdgcn_s_setprio(1);
      o0 = MFMA32(vf0, f0.v, o0);
      o0 = MFMA32(vf1, f1.v, o0);
      o1 = MFMA32(vf2, f0.v, o1);
      o1 = MFMA32(vf3, f1.v, o1);
      __builtin_amdgcn_s_setprio(0);
    }
    __syncthreads();
  }
  lsum += __shfl_xor(lsum, 32);
  float rl = 1.0f / lsum;
  int b = bh >> 3, h = bh & 7;
  unsigned short* aorow = ao + ((size_t)(b * 1024 + q0 + lq)) * 512 + h * 64;
  #pragma unroll
  for (int dt2 = 0; dt2 < 2; ++dt2) {
    #pragma unroll
    for (int g = 0; g < 4; ++g) {
      ushort4 pk;
      float v0 = (dt2 ? o1[4 * g + 0] : o0[4 * g + 0]) * rl;
      float v1 = (dt2 ? o1[4 * g + 1] : o0[4 * g + 1]) * rl;
      float v2 = (dt2 ? o1[4 * g + 2] : o0[4 * g + 2]) * rl;
      float v3 = (dt2 ? o1[4 * g + 3] : o0[4 * g + 3]) * rl;
      pk.x = f2bf(v0); pk.y = f2bf(v1); pk.z = f2bf(v2); pk.w = f2bf(v3);
      *(ushort4*)(aorow + dt2 * 32 + 8 * g + 4 * half) = pk;
    }
  }
}

// ---- kernel 6: output GEMM + bias, m97 structure --------------------------
__global__ __launch_bounds__(256) void k_out(const unsigned short* __restrict__ ao,
                                             const unsigned short* __restrict__ wot,
                                             const float* __restrict__ b_out,
                                             float* __restrict__ out) {
  __shared__ unsigned short As[128 * 32];
  __shared__ unsigned short Bs[128 * 32];
  int tid = threadIdx.x;
  int wid = tid >> 6, lane = tid & 63;
  int bm = blockIdx.x & 63, bn = blockIdx.x >> 6;   // 64 x 4
  int r0 = bm * 128, c0 = bn * 128;
  int lr = lane & 15, lk = (lane >> 4) * 8;
  int wr = (wid >> 1) * 64, wc = (wid & 1) * 64;
  int srow = lane >> 2, scol = (lane & 3) * 8;
  const unsigned short* gA0 = ao  + (size_t)(r0 + (wid * 2 + 0) * 16 + srow) * 512 + scol;
  const unsigned short* gA1 = ao  + (size_t)(r0 + (wid * 2 + 1) * 16 + srow) * 512 + scol;
  const unsigned short* gB0 = wot + (size_t)(c0 + (wid * 2 + 0) * 16 + srow) * 512 + scol;
  const unsigned short* gB1 = wot + (size_t)(c0 + (wid * 2 + 1) * 16 + srow) * 512 + scol;
  unsigned short* lA0 = &As[(wid * 2 + 0) * 512];
  unsigned short* lA1 = &As[(wid * 2 + 1) * 512];
  unsigned short* lB0 = &Bs[(wid * 2 + 0) * 512];
  unsigned short* lB1 = &Bs[(wid * 2 + 1) * 512];

  f32x4 acc[4][4];
  #pragma unroll
  for (int mi = 0; mi < 4; ++mi)
    #pragma unroll
    for (int ni = 0; ni < 4; ++ni)
      acc[mi][ni] = (f32x4){0.f, 0.f, 0.f, 0.f};

  for (int k0 = 0; k0 < 512; k0 += 32) {
    GLD16(gA0 + k0, lA0);
    GLD16(gA1 + k0, lA1);
    GLD16(gB0 + k0, lB0);
    GLD16(gB1 + k0, lB1);
    __syncthreads();
    bf16x8 af[4], bfr[4];
    #pragma unroll
    for (int mi = 0; mi < 4; ++mi)
      af[mi] = *(const bf16x8*)&As[(wr + mi * 16 + lr) * 32 + lk];
    #pragma unroll
    for (int ni = 0; ni < 4; ++ni)
      bfr[ni] = *(const bf16x8*)&Bs[(wc + ni * 16 + lr) * 32 + lk];
    #pragma unroll
    for (int mi = 0; mi < 4; ++mi)
      #pragma unroll
      for (int ni = 0; ni < 4; ++ni)
        acc[mi][ni] = MFMA16(af[mi], bfr[ni], acc[mi][ni]);
    __syncthreads();
  }

  #pragma unroll
  for (int ni = 0; ni < 4; ++ni) {
    int col = c0 + wc + ni * 16 + lr;
    float bias = b_out[col];
    #pragma unroll
    for (int mi = 0; mi < 4; ++mi)
      #pragma unroll
      for (int reg = 0; reg < 4; ++reg) {
        int row = r0 + wr + mi * 16 + (lane >> 4) * 4 + reg;
        out[(size_t)row * 512 + col] = acc[mi][ni][reg] + bias;
      }
  }
}

// ---------------------------------------------------------------------------
extern "C" void kernel_launch(void* const* d_in, const int* in_sizes, int n_in,
                              void* d_out, int out_size, void* d_ws, size_t ws_size,
                              hipStream_t stream) {
  const float* img       = (const float*)d_in[0];
  const float* tab       = (const float*)d_in[1];
  const float* w_qkv     = (const float*)d_in[2];
  const float* w_tab_qkv = (const float*)d_in[3];
  const float* w_out     = (const float*)d_in[4];
  const float* b_out     = (const float*)d_in[5];
  const float* ln_w      = (const float*)d_in[6];
  const float* ln_b      = (const float*)d_in[7];
  char* ws = (char*)d_ws;
  unsigned short* x_bf = (unsigned short*)(ws);             //  8 MiB
  unsigned short* wqt  = (unsigned short*)(ws + 8388608);   //  1.5 MiB
  unsigned short* wot  = (unsigned short*)(ws + 9961472);   //  0.5 MiB
  unsigned short* qh   = (unsigned short*)(ws + 10485760);  //  8 MiB
  unsigned short* kh   = (unsigned short*)(ws + 18874368);  //  8.5 MiB (KPAD)
  unsigned short* vt   = (unsigned short*)(ws + 27787264);  //  8.5 MiB (KPAD)
  unsigned short* ao   = (unsigned short*)(ws + 36700160);  //  8 MiB
  float*          t_ln = (float*)(ws + 45088768);           //  16 KiB
  float* out = (float*)d_out;

  hipLaunchKernelGGL(k_prep, dim3(256),  dim3(256), 0, stream, w_qkv, w_out, wqt, wot);
  hipLaunchKernelGGL(k_ln,   dim3(2050), dim3(256), 0, stream, img, tab, ln_w, ln_b, x_bf, t_ln);
  hipLaunchKernelGGL(k_tab,  dim3(128),  dim3(256), 0, stream, t_ln, w_tab_qkv, kh, vt);
  hipLaunchKernelGGL(k_qkv,  dim3(768),  dim3(256), 0, stream, x_bf, wqt, qh, kh, vt);
  hipLaunchKernelGGL(k_attn, dim3(256),  dim3(512), 0, stream, qh, kh, vt, ao);
  hipLaunchKernelGGL(k_out,  dim3(256),  dim3(256), 0, stream, ao, wot, b_out, out);
}

// Round 9
// 88.764 us; speedup vs baseline: 1.6731x; 1.1006x over previous
//
#include <hip/hip_runtime.h>

// ---------------------------------------------------------------------------
// Attention_43868795961547: LN -> QKV -> MHA(1025 keys) -> proj
// b=8, n=1024, dim=512, heads=8, dh=64. bf16 MFMA, f32 accum.
// Round 9: k_qkv/k_out converted to T3-minimum 2-phase pipeline:
// double-buffered LDS, STAGE(t+1) issued before compute(t), ONE barrier
// per K-step (was 2). Rest identical to round 8 (passing, 97.7us).
// ---------------------------------------------------------------------------

typedef __attribute__((ext_vector_type(4))) float f32x4;
typedef __attribute__((ext_vector_type(16))) float f32x16;
typedef __attribute__((ext_vector_type(8))) short bf16x8;
typedef __attribute__((ext_vector_type(8))) unsigned short u16x8;

#define MFMA16(a, b, c) __builtin_amdgcn_mfma_f32_16x16x32_bf16(a, b, c, 0, 0, 0)
#define MFMA32(a, b, c) __builtin_amdgcn_mfma_f32_32x32x16_bf16(a, b, c, 0, 0, 0)

#define GLD16(gsrc, ldst)                                                     \
  __builtin_amdgcn_global_load_lds(                                           \
      (const __attribute__((address_space(1))) void*)(gsrc),                  \
      (__attribute__((address_space(3))) void*)(ldst), 16, 0, 0)

#define KPAD 1088   // keys padded: 17 tiles of 64

// Q pre-scale: dots*0.125 in exp2-domain => fold 0.125*log2(e) into Q.
#define QSCALE 0.18033688011112042f

__device__ __forceinline__ unsigned short f2bf(float f) {
  union { float f; unsigned int u; } c; c.f = f;
  unsigned int u = c.u;
  u += 0x7fffu + ((u >> 16) & 1u);   // RNE
  return (unsigned short)(u >> 16);
}

__device__ __forceinline__ unsigned int cvtpk_bf16(float lo, float hi) {
  unsigned int r;
  asm("v_cvt_pk_bf16_f32 %0, %1, %2" : "=v"(r) : "v"(lo), "v"(hi));
  return r;
}

// ---- kernel 1: tiled transpose+convert weights to bf16 --------------------
__global__ __launch_bounds__(256) void k_prep(const float* __restrict__ w_qkv,
                                              const float* __restrict__ w_out,
                                              unsigned short* __restrict__ wqt,
                                              unsigned short* __restrict__ wot) {
  __shared__ unsigned short t[64][68];
  int blk = blockIdx.x, tid = threadIdx.x;
  const float* src;
  unsigned short* dst;
  int k0, n0, ldin;
  if (blk < 192) {
    int ti = blk / 24, tj = blk % 24;
    k0 = ti * 64; n0 = tj * 64; ldin = 1536;
    src = w_qkv; dst = wqt;
  } else {
    int g = blk - 192;
    int ti = g >> 3, tj = g & 7;
    k0 = ti * 64; n0 = tj * 64; ldin = 512;
    src = w_out; dst = wot;
  }
  int rr = tid >> 4, c4 = (tid & 15) * 4;
  #pragma unroll
  for (int i = 0; i < 4; ++i) {
    int r = i * 16 + rr;
    float4 v = *(const float4*)(src + (size_t)(k0 + r) * ldin + n0 + c4);
    t[c4 + 0][r] = f2bf(v.x);
    t[c4 + 1][r] = f2bf(v.y);
    t[c4 + 2][r] = f2bf(v.z);
    t[c4 + 3][r] = f2bf(v.w);
  }
  __syncthreads();
  #pragma unroll
  for (int i = 0; i < 4; ++i) {
    int r = i * 16 + rr;
    ushort4 w = *(const ushort4*)&t[r][c4];
    *(ushort4*)(dst + (size_t)(n0 + r) * 512 + k0 + c4) = w;
  }
}

// ---- kernel 2: LayerNorm (wave per row) -----------------------------------
__global__ __launch_bounds__(256) void k_ln(const float* __restrict__ img,
                                            const float* __restrict__ tab,
                                            const float* __restrict__ ln_w,
                                            const float* __restrict__ ln_b,
                                            unsigned short* __restrict__ x_bf,
                                            float* __restrict__ t_ln) {
  int wid = threadIdx.x >> 6, lane = threadIdx.x & 63;
  int row = blockIdx.x * 4 + wid;
  if (row >= 8200) return;
  const float* src = (row < 8192) ? img + (size_t)row * 512
                                  : tab + (size_t)(row - 8192) * 512;
  float4 v0 = *(const float4*)(src + lane * 8);
  float4 v1 = *(const float4*)(src + lane * 8 + 4);
  float x[8] = {v0.x, v0.y, v0.z, v0.w, v1.x, v1.y, v1.z, v1.w};
  float s = 0.f, sq = 0.f;
  #pragma unroll
  for (int j = 0; j < 8; ++j) { s += x[j]; sq += x[j] * x[j]; }
  #pragma unroll
  for (int off = 32; off >= 1; off >>= 1) {
    s  += __shfl_xor(s, off);
    sq += __shfl_xor(sq, off);
  }
  float mean = s * (1.0f / 512.0f);
  float var  = sq * (1.0f / 512.0f) - mean * mean;
  float rs = rsqrtf(var + 1e-5f);
  float4 w0 = *(const float4*)(ln_w + lane * 8);
  float4 w1 = *(const float4*)(ln_w + lane * 8 + 4);
  float4 b0 = *(const float4*)(ln_b + lane * 8);
  float4 b1 = *(const float4*)(ln_b + lane * 8 + 4);
  float w[8] = {w0.x, w0.y, w0.z, w0.w, w1.x, w1.y, w1.z, w1.w};
  float bb[8] = {b0.x, b0.y, b0.z, b0.w, b1.x, b1.y, b1.z, b1.w};
  float y[8];
  #pragma unroll
  for (int j = 0; j < 8; ++j) y[j] = (x[j] - mean) * rs * w[j] + bb[j];
  if (row < 8192) {
    bf16x8 o;
    #pragma unroll
    for (int j = 0; j < 8; ++j) o[j] = (short)f2bf(y[j]);
    *(bf16x8*)(x_bf + (size_t)row * 512 + lane * 8) = o;
  } else {
    float* dst = t_ln + (size_t)(row - 8192) * 512 + lane * 8;
    *(float4*)dst       = make_float4(y[0], y[1], y[2], y[3]);
    *(float4*)(dst + 4) = make_float4(y[4], y[5], y[6], y[7]);
  }
}

// ---- kernel 3: tab token k/v + pad zeroing (128 blocks) -------------------
__global__ __launch_bounds__(256) void k_tab(const float* __restrict__ t_ln,
                                             const float* __restrict__ w_tab,
                                             unsigned short* __restrict__ kh,
                                             unsigned short* __restrict__ vt) {
  __shared__ float red[4][64];
  int blk = blockIdx.x;            // 128 blocks
  int b = blk >> 4, chunk = blk & 15;
  int t = threadIdx.x;
  int cl = t & 63;                  // col within chunk
  int ks = t >> 6;                  // K-slice (one per wave)
  int col = chunk * 64 + cl;        // 0..1023 over [k | v] x [h] x [d]

  // ---- pad zeroing for this block's (bh) region ----
  {
    int h = chunk & 7;
    int bh = b * 8 + h;
    u16x8 z = (u16x8)(0);
    if (chunk < 8) {
      unsigned short* base = kh + ((size_t)bh * KPAD + 1024) * 64;
      #pragma unroll
      for (int i = 0; i < 2; ++i)
        *(u16x8*)(base + (t + i * 256) * 8) = z;
    } else {
      #pragma unroll
      for (int i = 0; i < 2; ++i) {
        int idx = t + i * 256;             // 0..511
        int d = idx >> 3, ch = idx & 7;
        *(u16x8*)(vt + ((size_t)bh * 64 + d) * KPAD + 1024 + ch * 8) = z;
      }
    }
  }

  // ---- tab GEMV (K-split across 4 waves) ----
  const float* tl = t_ln + b * 512;
  const float* wp = w_tab + 512 + col + (size_t)(ks * 128) * 1536;
  float s = 0.f;
  #pragma unroll 8
  for (int k = 0; k < 128; ++k)
    s += tl[ks * 128 + k] * wp[(size_t)k * 1536];
  red[ks][cl] = s;
  __syncthreads();
  if (ks == 0) {
    float v = red[0][cl] + red[1][cl] + red[2][cl] + red[3][cl];
    int part = col >> 9, hd = col & 511, h = hd >> 6, d = hd & 63;
    int bh = b * 8 + h;
    unsigned short hv = f2bf(v);
    if (part == 0) kh[((size_t)bh * KPAD + 1024) * 64 + d] = hv;
    else           vt[((size_t)bh * 64 + d) * KPAD + 1024] = hv;
  }
}

// ---- kernel 4: QKV GEMM, 2-phase pipelined (T3-minimum) -------------------
__global__ __launch_bounds__(256) void k_qkv(const unsigned short* __restrict__ x_bf,
                                             const unsigned short* __restrict__ wqt,
                                             unsigned short* __restrict__ qh,
                                             unsigned short* __restrict__ kh,
                                             unsigned short* __restrict__ vt) {
  __shared__ unsigned short As[2][128 * 32];
  __shared__ unsigned short Bs[2][128 * 32];
  int tid = threadIdx.x;
  int wid = tid >> 6, lane = tid & 63;
  int bm = blockIdx.x & 63, bn = blockIdx.x >> 6;   // 64 x 12
  int r0 = bm * 128, c0 = bn * 128;
  int lr = lane & 15, lk = (lane >> 4) * 8;
  int wr = (wid >> 1) * 64, wc = (wid & 1) * 64;
  int srow = lane >> 2, scol = (lane & 3) * 8;
  const unsigned short* gA0 = x_bf + (size_t)(r0 + (wid * 2 + 0) * 16 + srow) * 512 + scol;
  const unsigned short* gA1 = x_bf + (size_t)(r0 + (wid * 2 + 1) * 16 + srow) * 512 + scol;
  const unsigned short* gB0 = wqt  + (size_t)(c0 + (wid * 2 + 0) * 16 + srow) * 512 + scol;
  const unsigned short* gB1 = wqt  + (size_t)(c0 + (wid * 2 + 1) * 16 + srow) * 512 + scol;
  int o0 = (wid * 2 + 0) * 512, o1 = (wid * 2 + 1) * 512;

  f32x4 acc[4][4];
  #pragma unroll
  for (int mi = 0; mi < 4; ++mi)
    #pragma unroll
    for (int ni = 0; ni < 4; ++ni)
      acc[mi][ni] = (f32x4){0.f, 0.f, 0.f, 0.f};

  // prologue: stage k-step 0 into buffer 0
  GLD16(gA0, &As[0][o0]);
  GLD16(gA1, &As[0][o1]);
  GLD16(gB0, &Bs[0][o0]);
  GLD16(gB1, &Bs[0][o1]);
  __syncthreads();

  int cur = 0;
  for (int t = 0; t < 16; ++t) {
    if (t < 15) {
      int k1 = (t + 1) * 32;
      GLD16(gA0 + k1, &As[cur ^ 1][o0]);
      GLD16(gA1 + k1, &As[cur ^ 1][o1]);
      GLD16(gB0 + k1, &Bs[cur ^ 1][o0]);
      GLD16(gB1 + k1, &Bs[cur ^ 1][o1]);
    }
    bf16x8 af[4], bfr[4];
    #pragma unroll
    for (int mi = 0; mi < 4; ++mi)
      af[mi] = *(const bf16x8*)&As[cur][(wr + mi * 16 + lr) * 32 + lk];
    #pragma unroll
    for (int ni = 0; ni < 4; ++ni)
      bfr[ni] = *(const bf16x8*)&Bs[cur][(wc + ni * 16 + lr) * 32 + lk];
    __builtin_amdgcn_s_setprio(1);
    #pragma unroll
    for (int mi = 0; mi < 4; ++mi)
      #pragma unroll
      for (int ni = 0; ni < 4; ++ni)
        acc[mi][ni] = MFMA16(af[mi], bfr[ni], acc[mi][ni]);
    __builtin_amdgcn_s_setprio(0);
    __syncthreads();   // drains vmcnt -> next buffer ready
    cur ^= 1;
  }

  #pragma unroll
  for (int ni = 0; ni < 4; ++ni) {
    int col0 = c0 + wc + ni * 16;
    int which = col0 >> 9;
    int hh = (col0 & 511) >> 6;
    int d = (col0 & 63) + lr;
    #pragma unroll
    for (int mi = 0; mi < 4; ++mi)
      #pragma unroll
      for (int reg = 0; reg < 4; ++reg) {
        int row = r0 + wr + mi * 16 + (lane >> 4) * 4 + reg;
        int b = row >> 10, n = row & 1023;
        int bh = b * 8 + hh;
        float v = acc[mi][ni][reg];
        if (which == 0) {
          qh[((size_t)bh * 1024 + n) * 64 + d] = f2bf(v * QSCALE);
        } else if (which == 1) {
          kh[((size_t)bh * KPAD + n) * 64 + d] = f2bf(v);
        } else {
          vt[((size_t)bh * 64 + d) * KPAD + n] = f2bf(v);
        }
      }
  }
}

// ---- kernel 5: flash attention, 8-wave block + LDS-staged K/V -------------
__global__ __launch_bounds__(512, 4) void k_attn(const unsigned short* __restrict__ qh,
                                                 const unsigned short* __restrict__ kh,
                                                 const unsigned short* __restrict__ vt,
                                                 unsigned short* __restrict__ ao) {
  __shared__ __align__(16) unsigned short Ks[2][4096];  // [64 key][64 d] swz
  __shared__ __align__(16) unsigned short Vs[2][4096];  // [64 d][64 key] swz
  int tid = threadIdx.x;
  int wid = tid >> 6, lane = tid & 63;
  int bid = blockIdx.x;
  int swz = ((bid & 7) << 5) | (bid >> 3);   // bijective; 8 bh per XCD
  int bh = swz >> 2;
  int q0 = (swz & 3) * 256 + wid * 32;
  int lq = lane & 31, half = lane >> 5;

  const unsigned short* Q  = qh + (size_t)bh * 1024 * 64;
  const unsigned short* Kg = kh + (size_t)bh * KPAD * 64;
  const unsigned short* Vg = vt + (size_t)bh * 64 * KPAD;

  int xr = tid >> 3;
  int xc = (tid & 7) ^ (xr & 7);
  const unsigned short* kg_src = Kg + xr * 64 + xc * 8;
  const unsigned short* vg_src = Vg + (size_t)xr * KPAD + xc * 8;
  unsigned short* kdstA = &Ks[0][wid * 512];
  unsigned short* kdstB = &Ks[1][wid * 512];
  unsigned short* vdstA = &Vs[0][wid * 512];
  unsigned short* vdstB = &Vs[1][wid * 512];

  bf16x8 qf[4];
  const unsigned short* qlane = Q + (size_t)(q0 + lq) * 64 + half * 8;
  #pragma unroll
  for (int dt = 0; dt < 4; ++dt)
    qf[dt] = *(const bf16x8*)(qlane + dt * 16);

  f32x16 o0 = (f32x16)(0.0f), o1 = (f32x16)(0.0f);
  float m = -1e30f, lsum = 0.f;

  GLD16(kg_src, kdstA);
  GLD16(vg_src, vdstA);
  __syncthreads();

  for (int kt = 0; kt < 17; ++kt) {
    int cur = kt & 1;
    if (kt < 16) {
      GLD16(kg_src + (kt + 1) * 4096, cur ? kdstA : kdstB);
      GLD16(vg_src + (kt + 1) * 64,   cur ? vdstA : vdstB);
    }
    const unsigned short* Kb = Ks[cur];
    const unsigned short* Vb = Vs[cur];
    #pragma unroll
    for (int sub = 0; sub < 2; ++sub) {
      int krow = sub * 32 + lq;
      bf16x8 kf[4];
      #pragma unroll
      for (int dt = 0; dt < 4; ++dt) {
        int ch = (half + dt * 2) ^ (krow & 7);
        kf[dt] = *(const bf16x8*)&Kb[krow * 64 + ch * 8];
      }
      f32x16 s = (f32x16)(0.0f);
      __builtin_amdgcn_s_setprio(1);
      #pragma unroll
      for (int dt = 0; dt < 4; ++dt)
        s = MFMA32(kf[dt], qf[dt], s);
      __builtin_amdgcn_s_setprio(0);
      if (kt == 16) {
        if (sub == 0) {
          #pragma unroll
          for (int reg = 0; reg < 16; ++reg) {
            if (reg == 0) { if (half) s[0] = -1e30f; }
            else s[reg] = -1e30f;
          }
        } else {
          #pragma unroll
          for (int reg = 0; reg < 16; ++reg) s[reg] = -1e30f;
        }
      }
      float pmax = s[0];
      #pragma unroll
      for (int reg = 1; reg < 16; ++reg) pmax = fmaxf(pmax, s[reg]);
      pmax = fmaxf(pmax, __shfl_xor(pmax, 32));
      if (!__all(pmax <= m + 8.0f)) {
        float mnew = fmaxf(m, pmax);
        float al = __builtin_amdgcn_exp2f(m - mnew);
        lsum *= al;
        #pragma unroll
        for (int reg = 0; reg < 16; ++reg) { o0[reg] *= al; o1[reg] *= al; }
        m = mnew;
      }
      float p[16];
      float ls = 0.f;
      #pragma unroll
      for (int reg = 0; reg < 16; ++reg) {
        p[reg] = __builtin_amdgcn_exp2f(s[reg] - m);
        ls += p[reg];
      }
      lsum += ls;
      unsigned int c0x0 = cvtpk_bf16(p[0],  p[1]);
      unsigned int c0x1 = cvtpk_bf16(p[2],  p[3]);
      unsigned int c0y0 = cvtpk_bf16(p[4],  p[5]);
      unsigned int c0y1 = cvtpk_bf16(p[6],  p[7]);
      unsigned int c1x0 = cvtpk_bf16(p[8],  p[9]);
      unsigned int c1x1 = cvtpk_bf16(p[10], p[11]);
      unsigned int c1y0 = cvtpk_bf16(p[12], p[13]);
      unsigned int c1y1 = cvtpk_bf16(p[14], p[15]);
      asm volatile("v_permlane32_swap_b32 %0, %1" : "+v"(c0x0), "+v"(c0y0));
      asm volatile("v_permlane32_swap_b32 %0, %1" : "+v"(c0x1), "+v"(c0y1));
      asm volatile("v_permlane32_swap_b32 %0, %1" : "+v"(c1x0), "+v"(c1y0));
      asm volatile("v_permlane32_swap_b32 %0, %1" : "+v"(c1x1), "+v"(c1y1));
      union { unsigned int w[4]; bf16x8 v; } f0, f1;
      f0.w[0] = c0x0; f0.w[1] = c0x1; f0.w[2] = c0y0; f0.w[3] = c0y1;
      f1.w[0] = c1x0; f1.w[1] = c1x1; f1.w[2] = c1y0; f1.w[3] = c1y1;
      int vr0 = lq, vr1 = lq + 32;
      int cb = sub * 4 + half;
      bf16x8 vf0 = *(const bf16x8*)&Vb[vr0 * 64 + ((cb + 0) ^ (vr0 & 7)) * 8];
      bf16x8 vf1 = *(const bf16x8*)&Vb[vr0 * 64 + ((cb + 2) ^ (vr0 & 7)) * 8];
      bf16x8 vf2 = *(const bf16x8*)&Vb[vr1 * 64 + ((cb + 0) ^ (vr1 & 7)) * 8];
      bf16x8 vf3 = *(const bf16x8*)&Vb[vr1 * 64 + ((cb + 2) ^ (vr1 & 7)) * 8];
      __builtin_amdgcn_s_setprio(1);
      o0 = MFMA32(vf0, f0.v, o0);
      o0 = MFMA32(vf1, f1.v, o0);
      o1 = MFMA32(vf2, f0.v, o1);
      o1 = MFMA32(vf3, f1.v, o1);
      __builtin_amdgcn_s_setprio(0);
    }
    __syncthreads();
  }
  lsum += __shfl_xor(lsum, 32);
  float rl = 1.0f / lsum;
  int b = bh >> 3, h = bh & 7;
  unsigned short* aorow = ao + ((size_t)(b * 1024 + q0 + lq)) * 512 + h * 64;
  #pragma unroll
  for (int dt2 = 0; dt2 < 2; ++dt2) {
    #pragma unroll
    for (int g = 0; g < 4; ++g) {
      ushort4 pk;
      float v0 = (dt2 ? o1[4 * g + 0] : o0[4 * g + 0]) * rl;
      float v1 = (dt2 ? o1[4 * g + 1] : o0[4 * g + 1]) * rl;
      float v2 = (dt2 ? o1[4 * g + 2] : o0[4 * g + 2]) * rl;
      float v3 = (dt2 ? o1[4 * g + 3] : o0[4 * g + 3]) * rl;
      pk.x = f2bf(v0); pk.y = f2bf(v1); pk.z = f2bf(v2); pk.w = f2bf(v3);
      *(ushort4*)(aorow + dt2 * 32 + 8 * g + 4 * half) = pk;
    }
  }
}

// ---- kernel 6: output GEMM + bias, 2-phase pipelined ----------------------
__global__ __launch_bounds__(256) void k_out(const unsigned short* __restrict__ ao,
                                             const unsigned short* __restrict__ wot,
                                             const float* __restrict__ b_out,
                                             float* __restrict__ out) {
  __shared__ unsigned short As[2][128 * 32];
  __shared__ unsigned short Bs[2][128 * 32];
  int tid = threadIdx.x;
  int wid = tid >> 6, lane = tid & 63;
  int bm = blockIdx.x & 63, bn = blockIdx.x >> 6;   // 64 x 4
  int r0 = bm * 128, c0 = bn * 128;
  int lr = lane & 15, lk = (lane >> 4) * 8;
  int wr = (wid >> 1) * 64, wc = (wid & 1) * 64;
  int srow = lane >> 2, scol = (lane & 3) * 8;
  const unsigned short* gA0 = ao  + (size_t)(r0 + (wid * 2 + 0) * 16 + srow) * 512 + scol;
  const unsigned short* gA1 = ao  + (size_t)(r0 + (wid * 2 + 1) * 16 + srow) * 512 + scol;
  const unsigned short* gB0 = wot + (size_t)(c0 + (wid * 2 + 0) * 16 + srow) * 512 + scol;
  const unsigned short* gB1 = wot + (size_t)(c0 + (wid * 2 + 1) * 16 + srow) * 512 + scol;
  int o0 = (wid * 2 + 0) * 512, o1 = (wid * 2 + 1) * 512;

  f32x4 acc[4][4];
  #pragma unroll
  for (int mi = 0; mi < 4; ++mi)
    #pragma unroll
    for (int ni = 0; ni < 4; ++ni)
      acc[mi][ni] = (f32x4){0.f, 0.f, 0.f, 0.f};

  GLD16(gA0, &As[0][o0]);
  GLD16(gA1, &As[0][o1]);
  GLD16(gB0, &Bs[0][o0]);
  GLD16(gB1, &Bs[0][o1]);
  __syncthreads();

  int cur = 0;
  for (int t = 0; t < 16; ++t) {
    if (t < 15) {
      int k1 = (t + 1) * 32;
      GLD16(gA0 + k1, &As[cur ^ 1][o0]);
      GLD16(gA1 + k1, &As[cur ^ 1][o1]);
      GLD16(gB0 + k1, &Bs[cur ^ 1][o0]);
      GLD16(gB1 + k1, &Bs[cur ^ 1][o1]);
    }
    bf16x8 af[4], bfr[4];
    #pragma unroll
    for (int mi = 0; mi < 4; ++mi)
      af[mi] = *(const bf16x8*)&As[cur][(wr + mi * 16 + lr) * 32 + lk];
    #pragma unroll
    for (int ni = 0; ni < 4; ++ni)
      bfr[ni] = *(const bf16x8*)&Bs[cur][(wc + ni * 16 + lr) * 32 + lk];
    __builtin_amdgcn_s_setprio(1);
    #pragma unroll
    for (int mi = 0; mi < 4; ++mi)
      #pragma unroll
      for (int ni = 0; ni < 4; ++ni)
        acc[mi][ni] = MFMA16(af[mi], bfr[ni], acc[mi][ni]);
    __builtin_amdgcn_s_setprio(0);
    __syncthreads();
    cur ^= 1;
  }

  #pragma unroll
  for (int ni = 0; ni < 4; ++ni) {
    int col = c0 + wc + ni * 16 + lr;
    float bias = b_out[col];
    #pragma unroll
    for (int mi = 0; mi < 4; ++mi)
      #pragma unroll
      for (int reg = 0; reg < 4; ++reg) {
        int row = r0 + wr + mi * 16 + (lane >> 4) * 4 + reg;
        out[(size_t)row * 512 + col] = acc[mi][ni][reg] + bias;
      }
  }
}

// ---------------------------------------------------------------------------
extern "C" void kernel_launch(void* const* d_in, const int* in_sizes, int n_in,
                              void* d_out, int out_size, void* d_ws, size_t ws_size,
                              hipStream_t stream) {
  const float* img       = (const float*)d_in[0];
  const float* tab       = (const float*)d_in[1];
  const float* w_qkv     = (const float*)d_in[2];
  const float* w_tab_qkv = (const float*)d_in[3];
  const float* w_out     = (const float*)d_in[4];
  const float* b_out     = (const float*)d_in[5];
  const float* ln_w      = (const float*)d_in[6];
  const float* ln_b      = (const float*)d_in[7];
  char* ws = (char*)d_ws;
  unsigned short* x_bf = (unsigned short*)(ws);             //  8 MiB
  unsigned short* wqt  = (unsigned short*)(ws + 8388608);   //  1.5 MiB
  unsigned short* wot  = (unsigned short*)(ws + 9961472);   //  0.5 MiB
  unsigned short* qh   = (unsigned short*)(ws + 10485760);  //  8 MiB
  unsigned short* kh   = (unsigned short*)(ws + 18874368);  //  8.5 MiB (KPAD)
  unsigned short* vt   = (unsigned short*)(ws + 27787264);  //  8.5 MiB (KPAD)
  unsigned short* ao   = (unsigned short*)(ws + 36700160);  //  8 MiB
  float*          t_ln = (float*)(ws + 45088768);           //  16 KiB
  float* out = (float*)d_out;

  hipLaunchKernelGGL(k_prep, dim3(256),  dim3(256), 0, stream, w_qkv, w_out, wqt, wot);
  hipLaunchKernelGGL(k_ln,   dim3(2050), dim3(256), 0, stream, img, tab, ln_w, ln_b, x_bf, t_ln);
  hipLaunchKernelGGL(k_tab,  dim3(128),  dim3(256), 0, stream, t_ln, w_tab_qkv, kh, vt);
  hipLaunchKernelGGL(k_qkv,  dim3(768),  dim3(256), 0, stream, x_bf, wqt, qh, kh, vt);
  hipLaunchKernelGGL(k_attn, dim3(256),  dim3(512), 0, stream, qh, kh, vt, ao);
  hipLaunchKernelGGL(k_out,  dim3(256),  dim3(256), 0, stream, ao, wot, b_out, out);
}

// Round 10
// 88.719 us; speedup vs baseline: 1.6739x; 1.0005x over previous
//
#include <hip/hip_runtime.h>

// ---------------------------------------------------------------------------
// Attention_43868795961547: LN -> QKV -> MHA(1025 keys) -> proj
// b=8, n=1024, dim=512, heads=8, dh=64. bf16 MFMA, f32 accum.
// Round 10: k_qkv/k_out -> counted-vmcnt pipeline (T4): raw s_barrier +
// s_waitcnt vmcnt(4), 2-step-ahead prefetch, never drain to 0 in loop.
// Rest identical to round 9 (passing, 88.8us).
// ---------------------------------------------------------------------------

typedef __attribute__((ext_vector_type(4))) float f32x4;
typedef __attribute__((ext_vector_type(16))) float f32x16;
typedef __attribute__((ext_vector_type(8))) short bf16x8;
typedef __attribute__((ext_vector_type(8))) unsigned short u16x8;

#define MFMA16(a, b, c) __builtin_amdgcn_mfma_f32_16x16x32_bf16(a, b, c, 0, 0, 0)
#define MFMA32(a, b, c) __builtin_amdgcn_mfma_f32_32x32x16_bf16(a, b, c, 0, 0, 0)

#define GLD16(gsrc, ldst)                                                     \
  __builtin_amdgcn_global_load_lds(                                           \
      (const __attribute__((address_space(1))) void*)(gsrc),                  \
      (__attribute__((address_space(3))) void*)(ldst), 16, 0, 0)

#define KPAD 1088   // keys padded: 17 tiles of 64

// Q pre-scale: dots*0.125 in exp2-domain => fold 0.125*log2(e) into Q.
#define QSCALE 0.18033688011112042f

__device__ __forceinline__ unsigned short f2bf(float f) {
  union { float f; unsigned int u; } c; c.f = f;
  unsigned int u = c.u;
  u += 0x7fffu + ((u >> 16) & 1u);   // RNE
  return (unsigned short)(u >> 16);
}

__device__ __forceinline__ unsigned int cvtpk_bf16(float lo, float hi) {
  unsigned int r;
  asm("v_cvt_pk_bf16_f32 %0, %1, %2" : "=v"(r) : "v"(lo), "v"(hi));
  return r;
}

// ---- kernel 1: tiled transpose+convert weights to bf16 --------------------
__global__ __launch_bounds__(256) void k_prep(const float* __restrict__ w_qkv,
                                              const float* __restrict__ w_out,
                                              unsigned short* __restrict__ wqt,
                                              unsigned short* __restrict__ wot) {
  __shared__ unsigned short t[64][68];
  int blk = blockIdx.x, tid = threadIdx.x;
  const float* src;
  unsigned short* dst;
  int k0, n0, ldin;
  if (blk < 192) {
    int ti = blk / 24, tj = blk % 24;
    k0 = ti * 64; n0 = tj * 64; ldin = 1536;
    src = w_qkv; dst = wqt;
  } else {
    int g = blk - 192;
    int ti = g >> 3, tj = g & 7;
    k0 = ti * 64; n0 = tj * 64; ldin = 512;
    src = w_out; dst = wot;
  }
  int rr = tid >> 4, c4 = (tid & 15) * 4;
  #pragma unroll
  for (int i = 0; i < 4; ++i) {
    int r = i * 16 + rr;
    float4 v = *(const float4*)(src + (size_t)(k0 + r) * ldin + n0 + c4);
    t[c4 + 0][r] = f2bf(v.x);
    t[c4 + 1][r] = f2bf(v.y);
    t[c4 + 2][r] = f2bf(v.z);
    t[c4 + 3][r] = f2bf(v.w);
  }
  __syncthreads();
  #pragma unroll
  for (int i = 0; i < 4; ++i) {
    int r = i * 16 + rr;
    ushort4 w = *(const ushort4*)&t[r][c4];
    *(ushort4*)(dst + (size_t)(n0 + r) * 512 + k0 + c4) = w;
  }
}

// ---- kernel 2: LayerNorm (wave per row) -----------------------------------
__global__ __launch_bounds__(256) void k_ln(const float* __restrict__ img,
                                            const float* __restrict__ tab,
                                            const float* __restrict__ ln_w,
                                            const float* __restrict__ ln_b,
                                            unsigned short* __restrict__ x_bf,
                                            float* __restrict__ t_ln) {
  int wid = threadIdx.x >> 6, lane = threadIdx.x & 63;
  int row = blockIdx.x * 4 + wid;
  if (row >= 8200) return;
  const float* src = (row < 8192) ? img + (size_t)row * 512
                                  : tab + (size_t)(row - 8192) * 512;
  float4 v0 = *(const float4*)(src + lane * 8);
  float4 v1 = *(const float4*)(src + lane * 8 + 4);
  float x[8] = {v0.x, v0.y, v0.z, v0.w, v1.x, v1.y, v1.z, v1.w};
  float s = 0.f, sq = 0.f;
  #pragma unroll
  for (int j = 0; j < 8; ++j) { s += x[j]; sq += x[j] * x[j]; }
  #pragma unroll
  for (int off = 32; off >= 1; off >>= 1) {
    s  += __shfl_xor(s, off);
    sq += __shfl_xor(sq, off);
  }
  float mean = s * (1.0f / 512.0f);
  float var  = sq * (1.0f / 512.0f) - mean * mean;
  float rs = rsqrtf(var + 1e-5f);
  float4 w0 = *(const float4*)(ln_w + lane * 8);
  float4 w1 = *(const float4*)(ln_w + lane * 8 + 4);
  float4 b0 = *(const float4*)(ln_b + lane * 8);
  float4 b1 = *(const float4*)(ln_b + lane * 8 + 4);
  float w[8] = {w0.x, w0.y, w0.z, w0.w, w1.x, w1.y, w1.z, w1.w};
  float bb[8] = {b0.x, b0.y, b0.z, b0.w, b1.x, b1.y, b1.z, b1.w};
  float y[8];
  #pragma unroll
  for (int j = 0; j < 8; ++j) y[j] = (x[j] - mean) * rs * w[j] + bb[j];
  if (row < 8192) {
    bf16x8 o;
    #pragma unroll
    for (int j = 0; j < 8; ++j) o[j] = (short)f2bf(y[j]);
    *(bf16x8*)(x_bf + (size_t)row * 512 + lane * 8) = o;
  } else {
    float* dst = t_ln + (size_t)(row - 8192) * 512 + lane * 8;
    *(float4*)dst       = make_float4(y[0], y[1], y[2], y[3]);
    *(float4*)(dst + 4) = make_float4(y[4], y[5], y[6], y[7]);
  }
}

// ---- kernel 3: tab token k/v + pad zeroing (128 blocks) -------------------
__global__ __launch_bounds__(256) void k_tab(const float* __restrict__ t_ln,
                                             const float* __restrict__ w_tab,
                                             unsigned short* __restrict__ kh,
                                             unsigned short* __restrict__ vt) {
  __shared__ float red[4][64];
  int blk = blockIdx.x;            // 128 blocks
  int b = blk >> 4, chunk = blk & 15;
  int t = threadIdx.x;
  int cl = t & 63;                  // col within chunk
  int ks = t >> 6;                  // K-slice (one per wave)
  int col = chunk * 64 + cl;        // 0..1023 over [k | v] x [h] x [d]

  // ---- pad zeroing for this block's (bh) region ----
  {
    int h = chunk & 7;
    int bh = b * 8 + h;
    u16x8 z = (u16x8)(0);
    if (chunk < 8) {
      unsigned short* base = kh + ((size_t)bh * KPAD + 1024) * 64;
      #pragma unroll
      for (int i = 0; i < 2; ++i)
        *(u16x8*)(base + (t + i * 256) * 8) = z;
    } else {
      #pragma unroll
      for (int i = 0; i < 2; ++i) {
        int idx = t + i * 256;             // 0..511
        int d = idx >> 3, ch = idx & 7;
        *(u16x8*)(vt + ((size_t)bh * 64 + d) * KPAD + 1024 + ch * 8) = z;
      }
    }
  }

  // ---- tab GEMV (K-split across 4 waves) ----
  const float* tl = t_ln + b * 512;
  const float* wp = w_tab + 512 + col + (size_t)(ks * 128) * 1536;
  float s = 0.f;
  #pragma unroll 8
  for (int k = 0; k < 128; ++k)
    s += tl[ks * 128 + k] * wp[(size_t)k * 1536];
  red[ks][cl] = s;
  __syncthreads();
  if (ks == 0) {
    float v = red[0][cl] + red[1][cl] + red[2][cl] + red[3][cl];
    int part = col >> 9, hd = col & 511, h = hd >> 6, d = hd & 63;
    int bh = b * 8 + h;
    unsigned short hv = f2bf(v);
    if (part == 0) kh[((size_t)bh * KPAD + 1024) * 64 + d] = hv;
    else           vt[((size_t)bh * 64 + d) * KPAD + 1024] = hv;
  }
}

// ---- kernel 4: QKV GEMM, counted-vmcnt 2-buffer pipeline ------------------
__global__ __launch_bounds__(256) void k_qkv(const unsigned short* __restrict__ x_bf,
                                             const unsigned short* __restrict__ wqt,
                                             unsigned short* __restrict__ qh,
                                             unsigned short* __restrict__ kh,
                                             unsigned short* __restrict__ vt) {
  __shared__ unsigned short As[2][128 * 32];
  __shared__ unsigned short Bs[2][128 * 32];
  int tid = threadIdx.x;
  int wid = tid >> 6, lane = tid & 63;
  int bm = blockIdx.x & 63, bn = blockIdx.x >> 6;   // 64 x 12
  int r0 = bm * 128, c0 = bn * 128;
  int lr = lane & 15, lk = (lane >> 4) * 8;
  int wr = (wid >> 1) * 64, wc = (wid & 1) * 64;
  int srow = lane >> 2, scol = (lane & 3) * 8;
  const unsigned short* gA0 = x_bf + (size_t)(r0 + (wid * 2 + 0) * 16 + srow) * 512 + scol;
  const unsigned short* gA1 = x_bf + (size_t)(r0 + (wid * 2 + 1) * 16 + srow) * 512 + scol;
  const unsigned short* gB0 = wqt  + (size_t)(c0 + (wid * 2 + 0) * 16 + srow) * 512 + scol;
  const unsigned short* gB1 = wqt  + (size_t)(c0 + (wid * 2 + 1) * 16 + srow) * 512 + scol;
  int o0 = (wid * 2 + 0) * 512, o1 = (wid * 2 + 1) * 512;

  f32x4 acc[4][4];
  #pragma unroll
  for (int mi = 0; mi < 4; ++mi)
    #pragma unroll
    for (int ni = 0; ni < 4; ++ni)
      acc[mi][ni] = (f32x4){0.f, 0.f, 0.f, 0.f};

  // prologue: stage k-steps 0 (buf0) and 1 (buf1); issue order defines vmcnt age
  GLD16(gA0, &As[0][o0]);
  GLD16(gA1, &As[0][o1]);
  GLD16(gB0, &Bs[0][o0]);
  GLD16(gB1, &Bs[0][o1]);
  GLD16(gA0 + 32, &As[1][o0]);
  GLD16(gA1 + 32, &As[1][o1]);
  GLD16(gB0 + 32, &Bs[1][o0]);
  GLD16(gB1 + 32, &Bs[1][o1]);

  int cur = 0;
  for (int t = 0; t < 16; ++t) {
    // wait own tile-t loads (4 newest = t+1's may stay in flight), then align
    if (t < 15) asm volatile("s_waitcnt vmcnt(4)" ::: "memory");
    else        asm volatile("s_waitcnt vmcnt(0)" ::: "memory");
    __builtin_amdgcn_s_barrier();   // all waves' t-loads landed -> LDS ready
    bf16x8 af[4], bfr[4];
    #pragma unroll
    for (int mi = 0; mi < 4; ++mi)
      af[mi] = *(const bf16x8*)&As[cur][(wr + mi * 16 + lr) * 32 + lk];
    #pragma unroll
    for (int ni = 0; ni < 4; ++ni)
      bfr[ni] = *(const bf16x8*)&Bs[cur][(wc + ni * 16 + lr) * 32 + lk];
    __builtin_amdgcn_s_setprio(1);
    #pragma unroll
    for (int mi = 0; mi < 4; ++mi)
      #pragma unroll
      for (int ni = 0; ni < 4; ++ni)
        acc[mi][ni] = MFMA16(af[mi], bfr[ni], acc[mi][ni]);
    __builtin_amdgcn_s_setprio(0);
    __builtin_amdgcn_s_barrier();   // all waves done reading buf[cur]
    asm volatile("" ::: "memory");
    if (t < 14) {                   // refill buf[cur] with tile t+2
      int k2 = (t + 2) * 32;
      GLD16(gA0 + k2, &As[cur][o0]);
      GLD16(gA1 + k2, &As[cur][o1]);
      GLD16(gB0 + k2, &Bs[cur][o0]);
      GLD16(gB1 + k2, &Bs[cur][o1]);
    }
    cur ^= 1;
  }

  #pragma unroll
  for (int ni = 0; ni < 4; ++ni) {
    int col0 = c0 + wc + ni * 16;
    int which = col0 >> 9;
    int hh = (col0 & 511) >> 6;
    int d = (col0 & 63) + lr;
    #pragma unroll
    for (int mi = 0; mi < 4; ++mi)
      #pragma unroll
      for (int reg = 0; reg < 4; ++reg) {
        int row = r0 + wr + mi * 16 + (lane >> 4) * 4 + reg;
        int b = row >> 10, n = row & 1023;
        int bh = b * 8 + hh;
        float v = acc[mi][ni][reg];
        if (which == 0) {
          qh[((size_t)bh * 1024 + n) * 64 + d] = f2bf(v * QSCALE);
        } else if (which == 1) {
          kh[((size_t)bh * KPAD + n) * 64 + d] = f2bf(v);
        } else {
          vt[((size_t)bh * 64 + d) * KPAD + n] = f2bf(v);
        }
      }
  }
}

// ---- kernel 5: flash attention, 8-wave block + LDS-staged K/V -------------
__global__ __launch_bounds__(512, 4) void k_attn(const unsigned short* __restrict__ qh,
                                                 const unsigned short* __restrict__ kh,
                                                 const unsigned short* __restrict__ vt,
                                                 unsigned short* __restrict__ ao) {
  __shared__ __align__(16) unsigned short Ks[2][4096];  // [64 key][64 d] swz
  __shared__ __align__(16) unsigned short Vs[2][4096];  // [64 d][64 key] swz
  int tid = threadIdx.x;
  int wid = tid >> 6, lane = tid & 63;
  int bid = blockIdx.x;
  int swz = ((bid & 7) << 5) | (bid >> 3);   // bijective; 8 bh per XCD
  int bh = swz >> 2;
  int q0 = (swz & 3) * 256 + wid * 32;
  int lq = lane & 31, half = lane >> 5;

  const unsigned short* Q  = qh + (size_t)bh * 1024 * 64;
  const unsigned short* Kg = kh + (size_t)bh * KPAD * 64;
  const unsigned short* Vg = vt + (size_t)bh * 64 * KPAD;

  int xr = tid >> 3;
  int xc = (tid & 7) ^ (xr & 7);
  const unsigned short* kg_src = Kg + xr * 64 + xc * 8;
  const unsigned short* vg_src = Vg + (size_t)xr * KPAD + xc * 8;
  unsigned short* kdstA = &Ks[0][wid * 512];
  unsigned short* kdstB = &Ks[1][wid * 512];
  unsigned short* vdstA = &Vs[0][wid * 512];
  unsigned short* vdstB = &Vs[1][wid * 512];

  bf16x8 qf[4];
  const unsigned short* qlane = Q + (size_t)(q0 + lq) * 64 + half * 8;
  #pragma unroll
  for (int dt = 0; dt < 4; ++dt)
    qf[dt] = *(const bf16x8*)(qlane + dt * 16);

  f32x16 o0 = (f32x16)(0.0f), o1 = (f32x16)(0.0f);
  float m = -1e30f, lsum = 0.f;

  GLD16(kg_src, kdstA);
  GLD16(vg_src, vdstA);
  __syncthreads();

  for (int kt = 0; kt < 17; ++kt) {
    int cur = kt & 1;
    if (kt < 16) {
      GLD16(kg_src + (kt + 1) * 4096, cur ? kdstA : kdstB);
      GLD16(vg_src + (kt + 1) * 64,   cur ? vdstA : vdstB);
    }
    const unsigned short* Kb = Ks[cur];
    const unsigned short* Vb = Vs[cur];
    #pragma unroll
    for (int sub = 0; sub < 2; ++sub) {
      int krow = sub * 32 + lq;
      bf16x8 kf[4];
      #pragma unroll
      for (int dt = 0; dt < 4; ++dt) {
        int ch = (half + dt * 2) ^ (krow & 7);
        kf[dt] = *(const bf16x8*)&Kb[krow * 64 + ch * 8];
      }
      f32x16 s = (f32x16)(0.0f);
      __builtin_amdgcn_s_setprio(1);
      #pragma unroll
      for (int dt = 0; dt < 4; ++dt)
        s = MFMA32(kf[dt], qf[dt], s);
      __builtin_amdgcn_s_setprio(0);
      if (kt == 16) {
        if (sub == 0) {
          #pragma unroll
          for (int reg = 0; reg < 16; ++reg) {
            if (reg == 0) { if (half) s[0] = -1e30f; }
            else s[reg] = -1e30f;
          }
        } else {
          #pragma unroll
          for (int reg = 0; reg < 16; ++reg) s[reg] = -1e30f;
        }
      }
      float pmax = s[0];
      #pragma unroll
      for (int reg = 1; reg < 16; ++reg) pmax = fmaxf(pmax, s[reg]);
      pmax = fmaxf(pmax, __shfl_xor(pmax, 32));
      if (!__all(pmax <= m + 8.0f)) {
        float mnew = fmaxf(m, pmax);
        float al = __builtin_amdgcn_exp2f(m - mnew);
        lsum *= al;
        #pragma unroll
        for (int reg = 0; reg < 16; ++reg) { o0[reg] *= al; o1[reg] *= al; }
        m = mnew;
      }
      float p[16];
      float ls = 0.f;
      #pragma unroll
      for (int reg = 0; reg < 16; ++reg) {
        p[reg] = __builtin_amdgcn_exp2f(s[reg] - m);
        ls += p[reg];
      }
      lsum += ls;
      unsigned int c0x0 = cvtpk_bf16(p[0],  p[1]);
      unsigned int c0x1 = cvtpk_bf16(p[2],  p[3]);
      unsigned int c0y0 = cvtpk_bf16(p[4],  p[5]);
      unsigned int c0y1 = cvtpk_bf16(p[6],  p[7]);
      unsigned int c1x0 = cvtpk_bf16(p[8],  p[9]);
      unsigned int c1x1 = cvtpk_bf16(p[10], p[11]);
      unsigned int c1y0 = cvtpk_bf16(p[12], p[13]);
      unsigned int c1y1 = cvtpk_bf16(p[14], p[15]);
      asm volatile("v_permlane32_swap_b32 %0, %1" : "+v"(c0x0), "+v"(c0y0));
      asm volatile("v_permlane32_swap_b32 %0, %1" : "+v"(c0x1), "+v"(c0y1));
      asm volatile("v_permlane32_swap_b32 %0, %1" : "+v"(c1x0), "+v"(c1y0));
      asm volatile("v_permlane32_swap_b32 %0, %1" : "+v"(c1x1), "+v"(c1y1));
      union { unsigned int w[4]; bf16x8 v; } f0, f1;
      f0.w[0] = c0x0; f0.w[1] = c0x1; f0.w[2] = c0y0; f0.w[3] = c0y1;
      f1.w[0] = c1x0; f1.w[1] = c1x1; f1.w[2] = c1y0; f1.w[3] = c1y1;
      int vr0 = lq, vr1 = lq + 32;
      int cb = sub * 4 + half;
      bf16x8 vf0 = *(const bf16x8*)&Vb[vr0 * 64 + ((cb + 0) ^ (vr0 & 7)) * 8];
      bf16x8 vf1 = *(const bf16x8*)&Vb[vr0 * 64 + ((cb + 2) ^ (vr0 & 7)) * 8];
      bf16x8 vf2 = *(const bf16x8*)&Vb[vr1 * 64 + ((cb + 0) ^ (vr1 & 7)) * 8];
      bf16x8 vf3 = *(const bf16x8*)&Vb[vr1 * 64 + ((cb + 2) ^ (vr1 & 7)) * 8];
      __builtin_amdgcn_s_setprio(1);
      o0 = MFMA32(vf0, f0.v, o0);
      o0 = MFMA32(vf1, f1.v, o0);
      o1 = MFMA32(vf2, f0.v, o1);
      o1 = MFMA32(vf3, f1.v, o1);
      __builtin_amdgcn_s_setprio(0);
    }
    __syncthreads();
  }
  lsum += __shfl_xor(lsum, 32);
  float rl = 1.0f / lsum;
  int b = bh >> 3, h = bh & 7;
  unsigned short* aorow = ao + ((size_t)(b * 1024 + q0 + lq)) * 512 + h * 64;
  #pragma unroll
  for (int dt2 = 0; dt2 < 2; ++dt2) {
    #pragma unroll
    for (int g = 0; g < 4; ++g) {
      ushort4 pk;
      float v0 = (dt2 ? o1[4 * g + 0] : o0[4 * g + 0]) * rl;
      float v1 = (dt2 ? o1[4 * g + 1] : o0[4 * g + 1]) * rl;
      float v2 = (dt2 ? o1[4 * g + 2] : o0[4 * g + 2]) * rl;
      float v3 = (dt2 ? o1[4 * g + 3] : o0[4 * g + 3]) * rl;
      pk.x = f2bf(v0); pk.y = f2bf(v1); pk.z = f2bf(v2); pk.w = f2bf(v3);
      *(ushort4*)(aorow + dt2 * 32 + 8 * g + 4 * half) = pk;
    }
  }
}

// ---- kernel 6: output GEMM + bias, counted-vmcnt pipeline -----------------
__global__ __launch_bounds__(256) void k_out(const unsigned short* __restrict__ ao,
                                             const unsigned short* __restrict__ wot,
                                             const float* __restrict__ b_out,
                                             float* __restrict__ out) {
  __shared__ unsigned short As[2][128 * 32];
  __shared__ unsigned short Bs[2][128 * 32];
  int tid = threadIdx.x;
  int wid = tid >> 6, lane = tid & 63;
  int bm = blockIdx.x & 63, bn = blockIdx.x >> 6;   // 64 x 4
  int r0 = bm * 128, c0 = bn * 128;
  int lr = lane & 15, lk = (lane >> 4) * 8;
  int wr = (wid >> 1) * 64, wc = (wid & 1) * 64;
  int srow = lane >> 2, scol = (lane & 3) * 8;
  const unsigned short* gA0 = ao  + (size_t)(r0 + (wid * 2 + 0) * 16 + srow) * 512 + scol;
  const unsigned short* gA1 = ao  + (size_t)(r0 + (wid * 2 + 1) * 16 + srow) * 512 + scol;
  const unsigned short* gB0 = wot + (size_t)(c0 + (wid * 2 + 0) * 16 + srow) * 512 + scol;
  const unsigned short* gB1 = wot + (size_t)(c0 + (wid * 2 + 1) * 16 + srow) * 512 + scol;
  int o0 = (wid * 2 + 0) * 512, o1 = (wid * 2 + 1) * 512;

  f32x4 acc[4][4];
  #pragma unroll
  for (int mi = 0; mi < 4; ++mi)
    #pragma unroll
    for (int ni = 0; ni < 4; ++ni)
      acc[mi][ni] = (f32x4){0.f, 0.f, 0.f, 0.f};

  GLD16(gA0, &As[0][o0]);
  GLD16(gA1, &As[0][o1]);
  GLD16(gB0, &Bs[0][o0]);
  GLD16(gB1, &Bs[0][o1]);
  GLD16(gA0 + 32, &As[1][o0]);
  GLD16(gA1 + 32, &As[1][o1]);
  GLD16(gB0 + 32, &Bs[1][o0]);
  GLD16(gB1 + 32, &Bs[1][o1]);

  int cur = 0;
  for (int t = 0; t < 16; ++t) {
    if (t < 15) asm volatile("s_waitcnt vmcnt(4)" ::: "memory");
    else        asm volatile("s_waitcnt vmcnt(0)" ::: "memory");
    __builtin_amdgcn_s_barrier();
    bf16x8 af[4], bfr[4];
    #pragma unroll
    for (int mi = 0; mi < 4; ++mi)
      af[mi] = *(const bf16x8*)&As[cur][(wr + mi * 16 + lr) * 32 + lk];
    #pragma unroll
    for (int ni = 0; ni < 4; ++ni)
      bfr[ni] = *(const bf16x8*)&Bs[cur][(wc + ni * 16 + lr) * 32 + lk];
    __builtin_amdgcn_s_setprio(1);
    #pragma unroll
    for (int mi = 0; mi < 4; ++mi)
      #pragma unroll
      for (int ni = 0; ni < 4; ++ni)
        acc[mi][ni] = MFMA16(af[mi], bfr[ni], acc[mi][ni]);
    __builtin_amdgcn_s_setprio(0);
    __builtin_amdgcn_s_barrier();
    asm volatile("" ::: "memory");
    if (t < 14) {
      int k2 = (t + 2) * 32;
      GLD16(gA0 + k2, &As[cur][o0]);
      GLD16(gA1 + k2, &As[cur][o1]);
      GLD16(gB0 + k2, &Bs[cur][o0]);
      GLD16(gB1 + k2, &Bs[cur][o1]);
    }
    cur ^= 1;
  }

  #pragma unroll
  for (int ni = 0; ni < 4; ++ni) {
    int col = c0 + wc + ni * 16 + lr;
    float bias = b_out[col];
    #pragma unroll
    for (int mi = 0; mi < 4; ++mi)
      #pragma unroll
      for (int reg = 0; reg < 4; ++reg) {
        int row = r0 + wr + mi * 16 + (lane >> 4) * 4 + reg;
        out[(size_t)row * 512 + col] = acc[mi][ni][reg] + bias;
      }
  }
}

// ---------------------------------------------------------------------------
extern "C" void kernel_launch(void* const* d_in, const int* in_sizes, int n_in,
                              void* d_out, int out_size, void* d_ws, size_t ws_size,
                              hipStream_t stream) {
  const float* img       = (const float*)d_in[0];
  const float* tab       = (const float*)d_in[1];
  const float* w_qkv     = (const float*)d_in[2];
  const float* w_tab_qkv = (const float*)d_in[3];
  const float* w_out     = (const float*)d_in[4];
  const float* b_out     = (const float*)d_in[5];
  const float* ln_w      = (const float*)d_in[6];
  const float* ln_b      = (const float*)d_in[7];
  char* ws = (char*)d_ws;
  unsigned short* x_bf = (unsigned short*)(ws);             //  8 MiB
  unsigned short* wqt  = (unsigned short*)(ws + 8388608);   //  1.5 MiB
  unsigned short* wot  = (unsigned short*)(ws + 9961472);   //  0.5 MiB
  unsigned short* qh   = (unsigned short*)(ws + 10485760);  //  8 MiB
  unsigned short* kh   = (unsigned short*)(ws + 18874368);  //  8.5 MiB (KPAD)
  unsigned short* vt   = (unsigned short*)(ws + 27787264);  //  8.5 MiB (KPAD)
  unsigned short* ao   = (unsigned short*)(ws + 36700160);  //  8 MiB
  float*          t_ln = (float*)(ws + 45088768);           //  16 KiB
  float* out = (float*)d_out;

  hipLaunchKernelGGL(k_prep, dim3(256),  dim3(256), 0, stream, w_qkv, w_out, wqt, wot);
  hipLaunchKernelGGL(k_ln,   dim3(2050), dim3(256), 0, stream, img, tab, ln_w, ln_b, x_bf, t_ln);
  hipLaunchKernelGGL(k_tab,  dim3(128),  dim3(256), 0, stream, t_ln, w_tab_qkv, kh, vt);
  hipLaunchKernelGGL(k_qkv,  dim3(768),  dim3(256), 0, stream, x_bf, wqt, qh, kh, vt);
  hipLaunchKernelGGL(k_attn, dim3(256),  dim3(512), 0, stream, qh, kh, vt, ao);
  hipLaunchKernelGGL(k_out,  dim3(256),  dim3(256), 0, stream, ao, wot, b_out, out);
}

// Round 11
// 82.762 us; speedup vs baseline: 1.7944x; 1.0720x over previous
//
#include <hip/hip_runtime.h>

// ---------------------------------------------------------------------------
// Attention_43868795961547: LN -> QKV -> MHA(1025 keys) -> proj
// b=8, n=1024, dim=512, heads=8, dh=64. bf16 MFMA, f32 accum.
// Round 11: (1) k_prep+k_ln+k_tab fused into one dispatch (k_tab does its
// own tab-LN, removing the dependency); (2) k_qkv/k_out -> 3-buffer LDS
// ring, ONE barrier per K-step, counted vmcnt(4) (T3 completed).
// ---------------------------------------------------------------------------

typedef __attribute__((ext_vector_type(4))) float f32x4;
typedef __attribute__((ext_vector_type(16))) float f32x16;
typedef __attribute__((ext_vector_type(8))) short bf16x8;
typedef __attribute__((ext_vector_type(8))) unsigned short u16x8;

#define MFMA16(a, b, c) __builtin_amdgcn_mfma_f32_16x16x32_bf16(a, b, c, 0, 0, 0)
#define MFMA32(a, b, c) __builtin_amdgcn_mfma_f32_32x32x16_bf16(a, b, c, 0, 0, 0)

#define GLD16(gsrc, ldst)                                                     \
  __builtin_amdgcn_global_load_lds(                                           \
      (const __attribute__((address_space(1))) void*)(gsrc),                  \
      (__attribute__((address_space(3))) void*)(ldst), 16, 0, 0)

#define KPAD 1088   // keys padded: 17 tiles of 64

// Q pre-scale: dots*0.125 in exp2-domain => fold 0.125*log2(e) into Q.
#define QSCALE 0.18033688011112042f

__device__ __forceinline__ unsigned short f2bf(float f) {
  union { float f; unsigned int u; } c; c.f = f;
  unsigned int u = c.u;
  u += 0x7fffu + ((u >> 16) & 1u);   // RNE
  return (unsigned short)(u >> 16);
}

__device__ __forceinline__ unsigned int cvtpk_bf16(float lo, float hi) {
  unsigned int r;
  asm("v_cvt_pk_bf16_f32 %0, %1, %2" : "=v"(r) : "v"(lo), "v"(hi));
  return r;
}

// ---- kernel 1: fused pre-pass --------------------------------------------
// blocks 0..255     : weight transpose+convert (w_qkv -> wqt, w_out -> wot)
// blocks 256..2303  : img LayerNorm -> x_bf (4 rows/block, wave per row)
// blocks 2304..2431 : tab LN (self-contained) + tab k/v GEMV + pad zeroing
__global__ __launch_bounds__(256) void k_pre(const float* __restrict__ img,
                                             const float* __restrict__ tab,
                                             const float* __restrict__ w_qkv,
                                             const float* __restrict__ w_tab,
                                             const float* __restrict__ w_out,
                                             const float* __restrict__ ln_w,
                                             const float* __restrict__ ln_b,
                                             unsigned short* __restrict__ x_bf,
                                             unsigned short* __restrict__ wqt,
                                             unsigned short* __restrict__ wot,
                                             unsigned short* __restrict__ kh,
                                             unsigned short* __restrict__ vt) {
  int blk = blockIdx.x, tid = threadIdx.x;
  if (blk < 256) {
    // ---------------- weight transpose ----------------
    __shared__ unsigned short tbuf[64][68];
    const float* src;
    unsigned short* dst;
    int k0, n0, ldin;
    if (blk < 192) {
      int ti = blk / 24, tj = blk % 24;
      k0 = ti * 64; n0 = tj * 64; ldin = 1536;
      src = w_qkv; dst = wqt;
    } else {
      int g = blk - 192;
      int ti = g >> 3, tj = g & 7;
      k0 = ti * 64; n0 = tj * 64; ldin = 512;
      src = w_out; dst = wot;
    }
    int rr = tid >> 4, c4 = (tid & 15) * 4;
    #pragma unroll
    for (int i = 0; i < 4; ++i) {
      int r = i * 16 + rr;
      float4 v = *(const float4*)(src + (size_t)(k0 + r) * ldin + n0 + c4);
      tbuf[c4 + 0][r] = f2bf(v.x);
      tbuf[c4 + 1][r] = f2bf(v.y);
      tbuf[c4 + 2][r] = f2bf(v.z);
      tbuf[c4 + 3][r] = f2bf(v.w);
    }
    __syncthreads();
    #pragma unroll
    for (int i = 0; i < 4; ++i) {
      int r = i * 16 + rr;
      ushort4 w = *(const ushort4*)&tbuf[r][c4];
      *(ushort4*)(dst + (size_t)(n0 + r) * 512 + k0 + c4) = w;
    }
  } else if (blk < 2304) {
    // ---------------- img LayerNorm ----------------
    int wid = tid >> 6, lane = tid & 63;
    int row = (blk - 256) * 4 + wid;
    const float* src = img + (size_t)row * 512;
    float4 v0 = *(const float4*)(src + lane * 8);
    float4 v1 = *(const float4*)(src + lane * 8 + 4);
    float x[8] = {v0.x, v0.y, v0.z, v0.w, v1.x, v1.y, v1.z, v1.w};
    float s = 0.f, sq = 0.f;
    #pragma unroll
    for (int j = 0; j < 8; ++j) { s += x[j]; sq += x[j] * x[j]; }
    #pragma unroll
    for (int off = 32; off >= 1; off >>= 1) {
      s  += __shfl_xor(s, off);
      sq += __shfl_xor(sq, off);
    }
    float mean = s * (1.0f / 512.0f);
    float var  = sq * (1.0f / 512.0f) - mean * mean;
    float rs = rsqrtf(var + 1e-5f);
    float4 w0 = *(const float4*)(ln_w + lane * 8);
    float4 w1 = *(const float4*)(ln_w + lane * 8 + 4);
    float4 b0 = *(const float4*)(ln_b + lane * 8);
    float4 b1 = *(const float4*)(ln_b + lane * 8 + 4);
    float w[8] = {w0.x, w0.y, w0.z, w0.w, w1.x, w1.y, w1.z, w1.w};
    float bb[8] = {b0.x, b0.y, b0.z, b0.w, b1.x, b1.y, b1.z, b1.w};
    bf16x8 o;
    #pragma unroll
    for (int j = 0; j < 8; ++j)
      o[j] = (short)f2bf((x[j] - mean) * rs * w[j] + bb[j]);
    *(bf16x8*)(x_bf + (size_t)row * 512 + lane * 8) = o;
  } else {
    // ---------------- tab LN + k/v GEMV + pad zero ----------------
    __shared__ float tl[512];
    __shared__ float red[4][64];
    __shared__ float ws_[4], wq_[4];
    int blk2 = blk - 2304;           // 128 blocks
    int b = blk2 >> 4, chunk = blk2 & 15;
    int t = tid;
    int lane = t & 63, wid = t >> 6;
    int cl = t & 63;                  // col within chunk
    int ks = t >> 6;                  // K-slice (one per wave)
    int col = chunk * 64 + cl;        // 0..1023 over [k | v] x [h] x [d]

    // pad zeroing for this block's (bh) region (before any sync; token
    // write below is ordered after __syncthreads in the same block)
    {
      int h = chunk & 7;
      int bh = b * 8 + h;
      u16x8 z = (u16x8)(0);
      if (chunk < 8) {
        unsigned short* base = kh + ((size_t)bh * KPAD + 1024) * 64;
        #pragma unroll
        for (int i = 0; i < 2; ++i)
          *(u16x8*)(base + (t + i * 256) * 8) = z;
      } else {
        #pragma unroll
        for (int i = 0; i < 2; ++i) {
          int idx = t + i * 256;             // 0..511
          int d = idx >> 3, ch = idx & 7;
          *(u16x8*)(vt + ((size_t)bh * 64 + d) * KPAD + 1024 + ch * 8) = z;
        }
      }
    }

    // self-contained tab LayerNorm (row b of tab, 512 floats)
    float2 tv = *(const float2*)(tab + (size_t)b * 512 + t * 2);
    float s_ = tv.x + tv.y, q_ = tv.x * tv.x + tv.y * tv.y;
    #pragma unroll
    for (int off = 32; off >= 1; off >>= 1) {
      s_ += __shfl_xor(s_, off);
      q_ += __shfl_xor(q_, off);
    }
    if (lane == 0) { ws_[wid] = s_; wq_[wid] = q_; }
    __syncthreads();
    float S = ws_[0] + ws_[1] + ws_[2] + ws_[3];
    float Qq = wq_[0] + wq_[1] + wq_[2] + wq_[3];
    float mean = S * (1.0f / 512.0f);
    float var = Qq * (1.0f / 512.0f) - mean * mean;
    float rs = rsqrtf(var + 1e-5f);
    tl[t * 2 + 0] = (tv.x - mean) * rs * ln_w[t * 2 + 0] + ln_b[t * 2 + 0];
    tl[t * 2 + 1] = (tv.y - mean) * rs * ln_w[t * 2 + 1] + ln_b[t * 2 + 1];
    __syncthreads();

    // GEMV (K-split across 4 waves)
    const float* wp = w_tab + 512 + col + (size_t)(ks * 128) * 1536;
    float s = 0.f;
    #pragma unroll 8
    for (int k = 0; k < 128; ++k)
      s += tl[ks * 128 + k] * wp[(size_t)k * 1536];
    red[ks][cl] = s;
    __syncthreads();
    if (ks == 0) {
      float v = red[0][cl] + red[1][cl] + red[2][cl] + red[3][cl];
      int part = col >> 9, hd = col & 511, h = hd >> 6, d = hd & 63;
      int bh = b * 8 + h;
      unsigned short hv = f2bf(v);
      if (part == 0) kh[((size_t)bh * KPAD + 1024) * 64 + d] = hv;
      else           vt[((size_t)bh * 64 + d) * KPAD + 1024] = hv;
    }
  }
}

// ---- kernel 4: QKV GEMM, 3-ring LDS, 1 barrier/step, counted vmcnt --------
__global__ __launch_bounds__(256) void k_qkv(const unsigned short* __restrict__ x_bf,
                                             const unsigned short* __restrict__ wqt,
                                             unsigned short* __restrict__ qh,
                                             unsigned short* __restrict__ kh,
                                             unsigned short* __restrict__ vt) {
  __shared__ unsigned short As[3][128 * 32];
  __shared__ unsigned short Bs[3][128 * 32];
  int tid = threadIdx.x;
  int wid = tid >> 6, lane = tid & 63;
  int bm = blockIdx.x & 63, bn = blockIdx.x >> 6;   // 64 x 12
  int r0 = bm * 128, c0 = bn * 128;
  int lr = lane & 15, lk = (lane >> 4) * 8;
  int wr = (wid >> 1) * 64, wc = (wid & 1) * 64;
  int srow = lane >> 2, scol = (lane & 3) * 8;
  const unsigned short* gA0 = x_bf + (size_t)(r0 + (wid * 2 + 0) * 16 + srow) * 512 + scol;
  const unsigned short* gA1 = x_bf + (size_t)(r0 + (wid * 2 + 1) * 16 + srow) * 512 + scol;
  const unsigned short* gB0 = wqt  + (size_t)(c0 + (wid * 2 + 0) * 16 + srow) * 512 + scol;
  const unsigned short* gB1 = wqt  + (size_t)(c0 + (wid * 2 + 1) * 16 + srow) * 512 + scol;
  int o0 = (wid * 2 + 0) * 512, o1 = (wid * 2 + 1) * 512;

  f32x4 acc[4][4];
  #pragma unroll
  for (int mi = 0; mi < 4; ++mi)
    #pragma unroll
    for (int ni = 0; ni < 4; ++ni)
      acc[mi][ni] = (f32x4){0.f, 0.f, 0.f, 0.f};

  // prologue: stage tiles 0 (buf0) and 1 (buf1); issue order = vmcnt age
  GLD16(gA0, &As[0][o0]);
  GLD16(gA1, &As[0][o1]);
  GLD16(gB0, &Bs[0][o0]);
  GLD16(gB1, &Bs[0][o1]);
  GLD16(gA0 + 32, &As[1][o0]);
  GLD16(gA1 + 32, &As[1][o1]);
  GLD16(gB0 + 32, &Bs[1][o0]);
  GLD16(gB1 + 32, &Bs[1][o1]);

  int cur = 0, pre = 2;
  for (int t = 0; t < 16; ++t) {
    // own tile-t loads landed (4 newest = t+1's stay in flight)
    if (t < 15) asm volatile("s_waitcnt vmcnt(4)" ::: "memory");
    else        asm volatile("s_waitcnt vmcnt(0)" ::: "memory");
    __builtin_amdgcn_s_barrier();     // block-wide: tile t resident
    if (t < 14) {                     // stage tile t+2 into ring slot 'pre'
      int k2 = (t + 2) * 32;
      GLD16(gA0 + k2, &As[pre][o0]);
      GLD16(gA1 + k2, &As[pre][o1]);
      GLD16(gB0 + k2, &Bs[pre][o0]);
      GLD16(gB1 + k2, &Bs[pre][o1]);
    }
    bf16x8 af[4], bfr[4];
    #pragma unroll
    for (int mi = 0; mi < 4; ++mi)
      af[mi] = *(const bf16x8*)&As[cur][(wr + mi * 16 + lr) * 32 + lk];
    #pragma unroll
    for (int ni = 0; ni < 4; ++ni)
      bfr[ni] = *(const bf16x8*)&Bs[cur][(wc + ni * 16 + lr) * 32 + lk];
    __builtin_amdgcn_s_setprio(1);
    #pragma unroll
    for (int mi = 0; mi < 4; ++mi)
      #pragma unroll
      for (int ni = 0; ni < 4; ++ni)
        acc[mi][ni] = MFMA16(af[mi], bfr[ni], acc[mi][ni]);
    __builtin_amdgcn_s_setprio(0);
    cur = (cur == 2) ? 0 : cur + 1;
    pre = (pre == 2) ? 0 : pre + 1;
  }

  #pragma unroll
  for (int ni = 0; ni < 4; ++ni) {
    int col0 = c0 + wc + ni * 16;
    int which = col0 >> 9;
    int hh = (col0 & 511) >> 6;
    int d = (col0 & 63) + lr;
    #pragma unroll
    for (int mi = 0; mi < 4; ++mi)
      #pragma unroll
      for (int reg = 0; reg < 4; ++reg) {
        int row = r0 + wr + mi * 16 + (lane >> 4) * 4 + reg;
        int b = row >> 10, n = row & 1023;
        int bh = b * 8 + hh;
        float v = acc[mi][ni][reg];
        if (which == 0) {
          qh[((size_t)bh * 1024 + n) * 64 + d] = f2bf(v * QSCALE);
        } else if (which == 1) {
          kh[((size_t)bh * KPAD + n) * 64 + d] = f2bf(v);
        } else {
          vt[((size_t)bh * 64 + d) * KPAD + n] = f2bf(v);
        }
      }
  }
}

// ---- kernel 5: flash attention, 8-wave block + LDS-staged K/V -------------
__global__ __launch_bounds__(512, 4) void k_attn(const unsigned short* __restrict__ qh,
                                                 const unsigned short* __restrict__ kh,
                                                 const unsigned short* __restrict__ vt,
                                                 unsigned short* __restrict__ ao) {
  __shared__ __align__(16) unsigned short Ks[2][4096];  // [64 key][64 d] swz
  __shared__ __align__(16) unsigned short Vs[2][4096];  // [64 d][64 key] swz
  int tid = threadIdx.x;
  int wid = tid >> 6, lane = tid & 63;
  int bid = blockIdx.x;
  int swz = ((bid & 7) << 5) | (bid >> 3);   // bijective; 8 bh per XCD
  int bh = swz >> 2;
  int q0 = (swz & 3) * 256 + wid * 32;
  int lq = lane & 31, half = lane >> 5;

  const unsigned short* Q  = qh + (size_t)bh * 1024 * 64;
  const unsigned short* Kg = kh + (size_t)bh * KPAD * 64;
  const unsigned short* Vg = vt + (size_t)bh * 64 * KPAD;

  int xr = tid >> 3;
  int xc = (tid & 7) ^ (xr & 7);
  const unsigned short* kg_src = Kg + xr * 64 + xc * 8;
  const unsigned short* vg_src = Vg + (size_t)xr * KPAD + xc * 8;
  unsigned short* kdstA = &Ks[0][wid * 512];
  unsigned short* kdstB = &Ks[1][wid * 512];
  unsigned short* vdstA = &Vs[0][wid * 512];
  unsigned short* vdstB = &Vs[1][wid * 512];

  bf16x8 qf[4];
  const unsigned short* qlane = Q + (size_t)(q0 + lq) * 64 + half * 8;
  #pragma unroll
  for (int dt = 0; dt < 4; ++dt)
    qf[dt] = *(const bf16x8*)(qlane + dt * 16);

  f32x16 o0 = (f32x16)(0.0f), o1 = (f32x16)(0.0f);
  float m = -1e30f, lsum = 0.f;

  GLD16(kg_src, kdstA);
  GLD16(vg_src, vdstA);
  __syncthreads();

  for (int kt = 0; kt < 17; ++kt) {
    int cur = kt & 1;
    if (kt < 16) {
      GLD16(kg_src + (kt + 1) * 4096, cur ? kdstA : kdstB);
      GLD16(vg_src + (kt + 1) * 64,   cur ? vdstA : vdstB);
    }
    const unsigned short* Kb = Ks[cur];
    const unsigned short* Vb = Vs[cur];
    #pragma unroll
    for (int sub = 0; sub < 2; ++sub) {
      int krow = sub * 32 + lq;
      bf16x8 kf[4];
      #pragma unroll
      for (int dt = 0; dt < 4; ++dt) {
        int ch = (half + dt * 2) ^ (krow & 7);
        kf[dt] = *(const bf16x8*)&Kb[krow * 64 + ch * 8];
      }
      f32x16 s = (f32x16)(0.0f);
      __builtin_amdgcn_s_setprio(1);
      #pragma unroll
      for (int dt = 0; dt < 4; ++dt)
        s = MFMA32(kf[dt], qf[dt], s);
      __builtin_amdgcn_s_setprio(0);
      if (kt == 16) {
        if (sub == 0) {
          #pragma unroll
          for (int reg = 0; reg < 16; ++reg) {
            if (reg == 0) { if (half) s[0] = -1e30f; }
            else s[reg] = -1e30f;
          }
        } else {
          #pragma unroll
          for (int reg = 0; reg < 16; ++reg) s[reg] = -1e30f;
        }
      }
      float pmax = s[0];
      #pragma unroll
      for (int reg = 1; reg < 16; ++reg) pmax = fmaxf(pmax, s[reg]);
      pmax = fmaxf(pmax, __shfl_xor(pmax, 32));
      if (!__all(pmax <= m + 8.0f)) {
        float mnew = fmaxf(m, pmax);
        float al = __builtin_amdgcn_exp2f(m - mnew);
        lsum *= al;
        #pragma unroll
        for (int reg = 0; reg < 16; ++reg) { o0[reg] *= al; o1[reg] *= al; }
        m = mnew;
      }
      float p[16];
      float ls = 0.f;
      #pragma unroll
      for (int reg = 0; reg < 16; ++reg) {
        p[reg] = __builtin_amdgcn_exp2f(s[reg] - m);
        ls += p[reg];
      }
      lsum += ls;
      unsigned int c0x0 = cvtpk_bf16(p[0],  p[1]);
      unsigned int c0x1 = cvtpk_bf16(p[2],  p[3]);
      unsigned int c0y0 = cvtpk_bf16(p[4],  p[5]);
      unsigned int c0y1 = cvtpk_bf16(p[6],  p[7]);
      unsigned int c1x0 = cvtpk_bf16(p[8],  p[9]);
      unsigned int c1x1 = cvtpk_bf16(p[10], p[11]);
      unsigned int c1y0 = cvtpk_bf16(p[12], p[13]);
      unsigned int c1y1 = cvtpk_bf16(p[14], p[15]);
      asm volatile("v_permlane32_swap_b32 %0, %1" : "+v"(c0x0), "+v"(c0y0));
      asm volatile("v_permlane32_swap_b32 %0, %1" : "+v"(c0x1), "+v"(c0y1));
      asm volatile("v_permlane32_swap_b32 %0, %1" : "+v"(c1x0), "+v"(c1y0));
      asm volatile("v_permlane32_swap_b32 %0, %1" : "+v"(c1x1), "+v"(c1y1));
      union { unsigned int w[4]; bf16x8 v; } f0, f1;
      f0.w[0] = c0x0; f0.w[1] = c0x1; f0.w[2] = c0y0; f0.w[3] = c0y1;
      f1.w[0] = c1x0; f1.w[1] = c1x1; f1.w[2] = c1y0; f1.w[3] = c1y1;
      int vr0 = lq, vr1 = lq + 32;
      int cb = sub * 4 + half;
      bf16x8 vf0 = *(const bf16x8*)&Vb[vr0 * 64 + ((cb + 0) ^ (vr0 & 7)) * 8];
      bf16x8 vf1 = *(const bf16x8*)&Vb[vr0 * 64 + ((cb + 2) ^ (vr0 & 7)) * 8];
      bf16x8 vf2 = *(const bf16x8*)&Vb[vr1 * 64 + ((cb + 0) ^ (vr1 & 7)) * 8];
      bf16x8 vf3 = *(const bf16x8*)&Vb[vr1 * 64 + ((cb + 2) ^ (vr1 & 7)) * 8];
      __builtin_amdgcn_s_setprio(1);
      o0 = MFMA32(vf0, f0.v, o0);
      o0 = MFMA32(vf1, f1.v, o0);
      o1 = MFMA32(vf2, f0.v, o1);
      o1 = MFMA32(vf3, f1.v, o1);
      __builtin_amdgcn_s_setprio(0);
    }
    __syncthreads();
  }
  lsum += __shfl_xor(lsum, 32);
  float rl = 1.0f / lsum;
  int b = bh >> 3, h = bh & 7;
  unsigned short* aorow = ao + ((size_t)(b * 1024 + q0 + lq)) * 512 + h * 64;
  #pragma unroll
  for (int dt2 = 0; dt2 < 2; ++dt2) {
    #pragma unroll
    for (int g = 0; g < 4; ++g) {
      ushort4 pk;
      float v0 = (dt2 ? o1[4 * g + 0] : o0[4 * g + 0]) * rl;
      float v1 = (dt2 ? o1[4 * g + 1] : o0[4 * g + 1]) * rl;
      float v2 = (dt2 ? o1[4 * g + 2] : o0[4 * g + 2]) * rl;
      float v3 = (dt2 ? o1[4 * g + 3] : o0[4 * g + 3]) * rl;
      pk.x = f2bf(v0); pk.y = f2bf(v1); pk.z = f2bf(v2); pk.w = f2bf(v3);
      *(ushort4*)(aorow + dt2 * 32 + 8 * g + 4 * half) = pk;
    }
  }
}

// ---- kernel 6: output GEMM + bias, 3-ring counted-vmcnt -------------------
__global__ __launch_bounds__(256) void k_out(const unsigned short* __restrict__ ao,
                                             const unsigned short* __restrict__ wot,
                                             const float* __restrict__ b_out,
                                             float* __restrict__ out) {
  __shared__ unsigned short As[3][128 * 32];
  __shared__ unsigned short Bs[3][128 * 32];
  int tid = threadIdx.x;
  int wid = tid >> 6, lane = tid & 63;
  int bm = blockIdx.x & 63, bn = blockIdx.x >> 6;   // 64 x 4
  int r0 = bm * 128, c0 = bn * 128;
  int lr = lane & 15, lk = (lane >> 4) * 8;
  int wr = (wid >> 1) * 64, wc = (wid & 1) * 64;
  int srow = lane >> 2, scol = (lane & 3) * 8;
  const unsigned short* gA0 = ao  + (size_t)(r0 + (wid * 2 + 0) * 16 + srow) * 512 + scol;
  const unsigned short* gA1 = ao  + (size_t)(r0 + (wid * 2 + 1) * 16 + srow) * 512 + scol;
  const unsigned short* gB0 = wot + (size_t)(c0 + (wid * 2 + 0) * 16 + srow) * 512 + scol;
  const unsigned short* gB1 = wot + (size_t)(c0 + (wid * 2 + 1) * 16 + srow) * 512 + scol;
  int o0 = (wid * 2 + 0) * 512, o1 = (wid * 2 + 1) * 512;

  f32x4 acc[4][4];
  #pragma unroll
  for (int mi = 0; mi < 4; ++mi)
    #pragma unroll
    for (int ni = 0; ni < 4; ++ni)
      acc[mi][ni] = (f32x4){0.f, 0.f, 0.f, 0.f};

  GLD16(gA0, &As[0][o0]);
  GLD16(gA1, &As[0][o1]);
  GLD16(gB0, &Bs[0][o0]);
  GLD16(gB1, &Bs[0][o1]);
  GLD16(gA0 + 32, &As[1][o0]);
  GLD16(gA1 + 32, &As[1][o1]);
  GLD16(gB0 + 32, &Bs[1][o0]);
  GLD16(gB1 + 32, &Bs[1][o1]);

  int cur = 0, pre = 2;
  for (int t = 0; t < 16; ++t) {
    if (t < 15) asm volatile("s_waitcnt vmcnt(4)" ::: "memory");
    else        asm volatile("s_waitcnt vmcnt(0)" ::: "memory");
    __builtin_amdgcn_s_barrier();
    if (t < 14) {
      int k2 = (t + 2) * 32;
      GLD16(gA0 + k2, &As[pre][o0]);
      GLD16(gA1 + k2, &As[pre][o1]);
      GLD16(gB0 + k2, &Bs[pre][o0]);
      GLD16(gB1 + k2, &Bs[pre][o1]);
    }
    bf16x8 af[4], bfr[4];
    #pragma unroll
    for (int mi = 0; mi < 4; ++mi)
      af[mi] = *(const bf16x8*)&As[cur][(wr + mi * 16 + lr) * 32 + lk];
    #pragma unroll
    for (int ni = 0; ni < 4; ++ni)
      bfr[ni] = *(const bf16x8*)&Bs[cur][(wc + ni * 16 + lr) * 32 + lk];
    __builtin_amdgcn_s_setprio(1);
    #pragma unroll
    for (int mi = 0; mi < 4; ++mi)
      #pragma unroll
      for (int ni = 0; ni < 4; ++ni)
        acc[mi][ni] = MFMA16(af[mi], bfr[ni], acc[mi][ni]);
    __builtin_amdgcn_s_setprio(0);
    cur = (cur == 2) ? 0 : cur + 1;
    pre = (pre == 2) ? 0 : pre + 1;
  }

  #pragma unroll
  for (int ni = 0; ni < 4; ++ni) {
    int col = c0 + wc + ni * 16 + lr;
    float bias = b_out[col];
    #pragma unroll
    for (int mi = 0; mi < 4; ++mi)
      #pragma unroll
      for (int reg = 0; reg < 4; ++reg) {
        int row = r0 + wr + mi * 16 + (lane >> 4) * 4 + reg;
        out[(size_t)row * 512 + col] = acc[mi][ni][reg] + bias;
      }
  }
}

// ---------------------------------------------------------------------------
extern "C" void kernel_launch(void* const* d_in, const int* in_sizes, int n_in,
                              void* d_out, int out_size, void* d_ws, size_t ws_size,
                              hipStream_t stream) {
  const float* img       = (const float*)d_in[0];
  const float* tab       = (const float*)d_in[1];
  const float* w_qkv     = (const float*)d_in[2];
  const float* w_tab_qkv = (const float*)d_in[3];
  const float* w_out     = (const float*)d_in[4];
  const float* b_out     = (const float*)d_in[5];
  const float* ln_w      = (const float*)d_in[6];
  const float* ln_b      = (const float*)d_in[7];
  char* ws = (char*)d_ws;
  unsigned short* x_bf = (unsigned short*)(ws);             //  8 MiB
  unsigned short* wqt  = (unsigned short*)(ws + 8388608);   //  1.5 MiB
  unsigned short* wot  = (unsigned short*)(ws + 9961472);   //  0.5 MiB
  unsigned short* qh   = (unsigned short*)(ws + 10485760);  //  8 MiB
  unsigned short* kh   = (unsigned short*)(ws + 18874368);  //  8.5 MiB (KPAD)
  unsigned short* vt   = (unsigned short*)(ws + 27787264);  //  8.5 MiB (KPAD)
  unsigned short* ao   = (unsigned short*)(ws + 36700160);  //  8 MiB
  float* out = (float*)d_out;

  hipLaunchKernelGGL(k_pre,  dim3(2432), dim3(256), 0, stream,
                     img, tab, w_qkv, w_tab_qkv, w_out, ln_w, ln_b,
                     x_bf, wqt, wot, kh, vt);
  hipLaunchKernelGGL(k_qkv,  dim3(768),  dim3(256), 0, stream, x_bf, wqt, qh, kh, vt);
  hipLaunchKernelGGL(k_attn, dim3(256),  dim3(512), 0, stream, qh, kh, vt, ao);
  hipLaunchKernelGGL(k_out,  dim3(256),  dim3(256), 0, stream, ao, wot, b_out, out);
}

// Round 12
// 82.515 us; speedup vs baseline: 1.7998x; 1.0030x over previous
//
#include <hip/hip_runtime.h>

// ---------------------------------------------------------------------------
// Attention_43868795961547: LN -> QKV -> MHA(1025 keys) -> proj
// b=8, n=1024, dim=512, heads=8, dh=64. bf16 MFMA, f32 accum.
// Round 12: k_qkv/k_out -> 8 waves/block (512 thr, wave=64x32), 24 waves/CU
// for stall hiding; 3-ring LDS + counted vmcnt(2) kept. k_pre/k_attn as r11.
// ---------------------------------------------------------------------------

typedef __attribute__((ext_vector_type(4))) float f32x4;
typedef __attribute__((ext_vector_type(16))) float f32x16;
typedef __attribute__((ext_vector_type(8))) short bf16x8;
typedef __attribute__((ext_vector_type(8))) unsigned short u16x8;

#define MFMA16(a, b, c) __builtin_amdgcn_mfma_f32_16x16x32_bf16(a, b, c, 0, 0, 0)
#define MFMA32(a, b, c) __builtin_amdgcn_mfma_f32_32x32x16_bf16(a, b, c, 0, 0, 0)

#define GLD16(gsrc, ldst)                                                     \
  __builtin_amdgcn_global_load_lds(                                           \
      (const __attribute__((address_space(1))) void*)(gsrc),                  \
      (__attribute__((address_space(3))) void*)(ldst), 16, 0, 0)

#define KPAD 1088   // keys padded: 17 tiles of 64

// Q pre-scale: dots*0.125 in exp2-domain => fold 0.125*log2(e) into Q.
#define QSCALE 0.18033688011112042f

__device__ __forceinline__ unsigned short f2bf(float f) {
  union { float f; unsigned int u; } c; c.f = f;
  unsigned int u = c.u;
  u += 0x7fffu + ((u >> 16) & 1u);   // RNE
  return (unsigned short)(u >> 16);
}

__device__ __forceinline__ unsigned int cvtpk_bf16(float lo, float hi) {
  unsigned int r;
  asm("v_cvt_pk_bf16_f32 %0, %1, %2" : "=v"(r) : "v"(lo), "v"(hi));
  return r;
}

// ---- kernel 1: fused pre-pass --------------------------------------------
__global__ __launch_bounds__(256) void k_pre(const float* __restrict__ img,
                                             const float* __restrict__ tab,
                                             const float* __restrict__ w_qkv,
                                             const float* __restrict__ w_tab,
                                             const float* __restrict__ w_out,
                                             const float* __restrict__ ln_w,
                                             const float* __restrict__ ln_b,
                                             unsigned short* __restrict__ x_bf,
                                             unsigned short* __restrict__ wqt,
                                             unsigned short* __restrict__ wot,
                                             unsigned short* __restrict__ kh,
                                             unsigned short* __restrict__ vt) {
  int blk = blockIdx.x, tid = threadIdx.x;
  if (blk < 256) {
    __shared__ unsigned short tbuf[64][68];
    const float* src;
    unsigned short* dst;
    int k0, n0, ldin;
    if (blk < 192) {
      int ti = blk / 24, tj = blk % 24;
      k0 = ti * 64; n0 = tj * 64; ldin = 1536;
      src = w_qkv; dst = wqt;
    } else {
      int g = blk - 192;
      int ti = g >> 3, tj = g & 7;
      k0 = ti * 64; n0 = tj * 64; ldin = 512;
      src = w_out; dst = wot;
    }
    int rr = tid >> 4, c4 = (tid & 15) * 4;
    #pragma unroll
    for (int i = 0; i < 4; ++i) {
      int r = i * 16 + rr;
      float4 v = *(const float4*)(src + (size_t)(k0 + r) * ldin + n0 + c4);
      tbuf[c4 + 0][r] = f2bf(v.x);
      tbuf[c4 + 1][r] = f2bf(v.y);
      tbuf[c4 + 2][r] = f2bf(v.z);
      tbuf[c4 + 3][r] = f2bf(v.w);
    }
    __syncthreads();
    #pragma unroll
    for (int i = 0; i < 4; ++i) {
      int r = i * 16 + rr;
      ushort4 w = *(const ushort4*)&tbuf[r][c4];
      *(ushort4*)(dst + (size_t)(n0 + r) * 512 + k0 + c4) = w;
    }
  } else if (blk < 2304) {
    int wid = tid >> 6, lane = tid & 63;
    int row = (blk - 256) * 4 + wid;
    const float* src = img + (size_t)row * 512;
    float4 v0 = *(const float4*)(src + lane * 8);
    float4 v1 = *(const float4*)(src + lane * 8 + 4);
    float x[8] = {v0.x, v0.y, v0.z, v0.w, v1.x, v1.y, v1.z, v1.w};
    float s = 0.f, sq = 0.f;
    #pragma unroll
    for (int j = 0; j < 8; ++j) { s += x[j]; sq += x[j] * x[j]; }
    #pragma unroll
    for (int off = 32; off >= 1; off >>= 1) {
      s  += __shfl_xor(s, off);
      sq += __shfl_xor(sq, off);
    }
    float mean = s * (1.0f / 512.0f);
    float var  = sq * (1.0f / 512.0f) - mean * mean;
    float rs = rsqrtf(var + 1e-5f);
    float4 w0 = *(const float4*)(ln_w + lane * 8);
    float4 w1 = *(const float4*)(ln_w + lane * 8 + 4);
    float4 b0 = *(const float4*)(ln_b + lane * 8);
    float4 b1 = *(const float4*)(ln_b + lane * 8 + 4);
    float w[8] = {w0.x, w0.y, w0.z, w0.w, w1.x, w1.y, w1.z, w1.w};
    float bb[8] = {b0.x, b0.y, b0.z, b0.w, b1.x, b1.y, b1.z, b1.w};
    bf16x8 o;
    #pragma unroll
    for (int j = 0; j < 8; ++j)
      o[j] = (short)f2bf((x[j] - mean) * rs * w[j] + bb[j]);
    *(bf16x8*)(x_bf + (size_t)row * 512 + lane * 8) = o;
  } else {
    __shared__ float tl[512];
    __shared__ float red[4][64];
    __shared__ float ws_[4], wq_[4];
    int blk2 = blk - 2304;           // 128 blocks
    int b = blk2 >> 4, chunk = blk2 & 15;
    int t = tid;
    int lane = t & 63, wid = t >> 6;
    int cl = t & 63;
    int ks = t >> 6;
    int col = chunk * 64 + cl;

    {
      int h = chunk & 7;
      int bh = b * 8 + h;
      u16x8 z = (u16x8)(0);
      if (chunk < 8) {
        unsigned short* base = kh + ((size_t)bh * KPAD + 1024) * 64;
        #pragma unroll
        for (int i = 0; i < 2; ++i)
          *(u16x8*)(base + (t + i * 256) * 8) = z;
      } else {
        #pragma unroll
        for (int i = 0; i < 2; ++i) {
          int idx = t + i * 256;
          int d = idx >> 3, ch = idx & 7;
          *(u16x8*)(vt + ((size_t)bh * 64 + d) * KPAD + 1024 + ch * 8) = z;
        }
      }
    }

    float2 tv = *(const float2*)(tab + (size_t)b * 512 + t * 2);
    float s_ = tv.x + tv.y, q_ = tv.x * tv.x + tv.y * tv.y;
    #pragma unroll
    for (int off = 32; off >= 1; off >>= 1) {
      s_ += __shfl_xor(s_, off);
      q_ += __shfl_xor(q_, off);
    }
    if (lane == 0) { ws_[wid] = s_; wq_[wid] = q_; }
    __syncthreads();
    float S = ws_[0] + ws_[1] + ws_[2] + ws_[3];
    float Qq = wq_[0] + wq_[1] + wq_[2] + wq_[3];
    float mean = S * (1.0f / 512.0f);
    float var = Qq * (1.0f / 512.0f) - mean * mean;
    float rs = rsqrtf(var + 1e-5f);
    tl[t * 2 + 0] = (tv.x - mean) * rs * ln_w[t * 2 + 0] + ln_b[t * 2 + 0];
    tl[t * 2 + 1] = (tv.y - mean) * rs * ln_w[t * 2 + 1] + ln_b[t * 2 + 1];
    __syncthreads();

    const float* wp = w_tab + 512 + col + (size_t)(ks * 128) * 1536;
    float s = 0.f;
    #pragma unroll 8
    for (int k = 0; k < 128; ++k)
      s += tl[ks * 128 + k] * wp[(size_t)k * 1536];
    red[ks][cl] = s;
    __syncthreads();
    if (ks == 0) {
      float v = red[0][cl] + red[1][cl] + red[2][cl] + red[3][cl];
      int part = col >> 9, hd = col & 511, h = hd >> 6, d = hd & 63;
      int bh = b * 8 + h;
      unsigned short hv = f2bf(v);
      if (part == 0) kh[((size_t)bh * KPAD + 1024) * 64 + d] = hv;
      else           vt[((size_t)bh * 64 + d) * KPAD + 1024] = hv;
    }
  }
}

// ---- kernel 4: QKV GEMM, 8 waves (64x32/wave), 3-ring, counted vmcnt ------
__global__ __launch_bounds__(512, 6) void k_qkv(const unsigned short* __restrict__ x_bf,
                                                const unsigned short* __restrict__ wqt,
                                                unsigned short* __restrict__ qh,
                                                unsigned short* __restrict__ kh,
                                                unsigned short* __restrict__ vt) {
  __shared__ unsigned short As[3][128 * 32];
  __shared__ unsigned short Bs[3][128 * 32];
  int tid = threadIdx.x;                    // 0..511
  int wid = tid >> 6, lane = tid & 63;
  int bm = blockIdx.x & 63, bn = blockIdx.x >> 6;   // 64 x 12
  int r0 = bm * 128, c0 = bn * 128;
  int lr = lane & 15, lk = (lane >> 4) * 8;
  int wr = (wid >> 2) * 64, wc = (wid & 3) * 32;    // 2M x 4N wave grid
  int srow = tid >> 2, scol = (tid & 3) * 8;        // 1 x 16B per matrix/thread
  const unsigned short* gA = x_bf + (size_t)(r0 + srow) * 512 + scol;
  const unsigned short* gB = wqt  + (size_t)(c0 + srow) * 512 + scol;
  int ldsoff = tid * 8;                     // linear dest (shorts)

  f32x4 acc[4][2];
  #pragma unroll
  for (int mi = 0; mi < 4; ++mi)
    #pragma unroll
    for (int ni = 0; ni < 2; ++ni)
      acc[mi][ni] = (f32x4){0.f, 0.f, 0.f, 0.f};

  // prologue: stage tiles 0 and 1 (per-wave outstanding = 4)
  GLD16(gA,      &As[0][ldsoff]);
  GLD16(gB,      &Bs[0][ldsoff]);
  GLD16(gA + 32, &As[1][ldsoff]);
  GLD16(gB + 32, &Bs[1][ldsoff]);

  int cur = 0, pre = 2;
  for (int t = 0; t < 16; ++t) {
    if (t < 15) asm volatile("s_waitcnt vmcnt(2)" ::: "memory");
    else        asm volatile("s_waitcnt vmcnt(0)" ::: "memory");
    __builtin_amdgcn_s_barrier();           // tile t resident block-wide
    if (t < 14) {
      int k2 = (t + 2) * 32;
      GLD16(gA + k2, &As[pre][ldsoff]);
      GLD16(gB + k2, &Bs[pre][ldsoff]);
    }
    bf16x8 af[4], bfr[2];
    #pragma unroll
    for (int mi = 0; mi < 4; ++mi)
      af[mi] = *(const bf16x8*)&As[cur][(wr + mi * 16 + lr) * 32 + lk];
    #pragma unroll
    for (int ni = 0; ni < 2; ++ni)
      bfr[ni] = *(const bf16x8*)&Bs[cur][(wc + ni * 16 + lr) * 32 + lk];
    __builtin_amdgcn_s_setprio(1);
    #pragma unroll
    for (int mi = 0; mi < 4; ++mi)
      #pragma unroll
      for (int ni = 0; ni < 2; ++ni)
        acc[mi][ni] = MFMA16(af[mi], bfr[ni], acc[mi][ni]);
    __builtin_amdgcn_s_setprio(0);
    cur = (cur == 2) ? 0 : cur + 1;
    pre = (pre == 2) ? 0 : pre + 1;
  }

  #pragma unroll
  for (int ni = 0; ni < 2; ++ni) {
    int col0 = c0 + wc + ni * 16;
    int which = col0 >> 9;
    int hh = (col0 & 511) >> 6;
    int d = (col0 & 63) + lr;
    #pragma unroll
    for (int mi = 0; mi < 4; ++mi)
      #pragma unroll
      for (int reg = 0; reg < 4; ++reg) {
        int row = r0 + wr + mi * 16 + (lane >> 4) * 4 + reg;
        int b = row >> 10, n = row & 1023;
        int bh = b * 8 + hh;
        float v = acc[mi][ni][reg];
        if (which == 0) {
          qh[((size_t)bh * 1024 + n) * 64 + d] = f2bf(v * QSCALE);
        } else if (which == 1) {
          kh[((size_t)bh * KPAD + n) * 64 + d] = f2bf(v);
        } else {
          vt[((size_t)bh * 64 + d) * KPAD + n] = f2bf(v);
        }
      }
  }
}

// ---- kernel 5: flash attention, 8-wave block + LDS-staged K/V -------------
__global__ __launch_bounds__(512, 4) void k_attn(const unsigned short* __restrict__ qh,
                                                 const unsigned short* __restrict__ kh,
                                                 const unsigned short* __restrict__ vt,
                                                 unsigned short* __restrict__ ao) {
  __shared__ __align__(16) unsigned short Ks[2][4096];  // [64 key][64 d] swz
  __shared__ __align__(16) unsigned short Vs[2][4096];  // [64 d][64 key] swz
  int tid = threadIdx.x;
  int wid = tid >> 6, lane = tid & 63;
  int bid = blockIdx.x;
  int swz = ((bid & 7) << 5) | (bid >> 3);   // bijective; 8 bh per XCD
  int bh = swz >> 2;
  int q0 = (swz & 3) * 256 + wid * 32;
  int lq = lane & 31, half = lane >> 5;

  const unsigned short* Q  = qh + (size_t)bh * 1024 * 64;
  const unsigned short* Kg = kh + (size_t)bh * KPAD * 64;
  const unsigned short* Vg = vt + (size_t)bh * 64 * KPAD;

  int xr = tid >> 3;
  int xc = (tid & 7) ^ (xr & 7);
  const unsigned short* kg_src = Kg + xr * 64 + xc * 8;
  const unsigned short* vg_src = Vg + (size_t)xr * KPAD + xc * 8;
  unsigned short* kdstA = &Ks[0][wid * 512];
  unsigned short* kdstB = &Ks[1][wid * 512];
  unsigned short* vdstA = &Vs[0][wid * 512];
  unsigned short* vdstB = &Vs[1][wid * 512];

  bf16x8 qf[4];
  const unsigned short* qlane = Q + (size_t)(q0 + lq) * 64 + half * 8;
  #pragma unroll
  for (int dt = 0; dt < 4; ++dt)
    qf[dt] = *(const bf16x8*)(qlane + dt * 16);

  f32x16 o0 = (f32x16)(0.0f), o1 = (f32x16)(0.0f);
  float m = -1e30f, lsum = 0.f;

  GLD16(kg_src, kdstA);
  GLD16(vg_src, vdstA);
  __syncthreads();

  for (int kt = 0; kt < 17; ++kt) {
    int cur = kt & 1;
    if (kt < 16) {
      GLD16(kg_src + (kt + 1) * 4096, cur ? kdstA : kdstB);
      GLD16(vg_src + (kt + 1) * 64,   cur ? vdstA : vdstB);
    }
    const unsigned short* Kb = Ks[cur];
    const unsigned short* Vb = Vs[cur];
    #pragma unroll
    for (int sub = 0; sub < 2; ++sub) {
      int krow = sub * 32 + lq;
      bf16x8 kf[4];
      #pragma unroll
      for (int dt = 0; dt < 4; ++dt) {
        int ch = (half + dt * 2) ^ (krow & 7);
        kf[dt] = *(const bf16x8*)&Kb[krow * 64 + ch * 8];
      }
      f32x16 s = (f32x16)(0.0f);
      __builtin_amdgcn_s_setprio(1);
      #pragma unroll
      for (int dt = 0; dt < 4; ++dt)
        s = MFMA32(kf[dt], qf[dt], s);
      __builtin_amdgcn_s_setprio(0);
      if (kt == 16) {
        if (sub == 0) {
          #pragma unroll
          for (int reg = 0; reg < 16; ++reg) {
            if (reg == 0) { if (half) s[0] = -1e30f; }
            else s[reg] = -1e30f;
          }
        } else {
          #pragma unroll
          for (int reg = 0; reg < 16; ++reg) s[reg] = -1e30f;
        }
      }
      float pmax = s[0];
      #pragma unroll
      for (int reg = 1; reg < 16; ++reg) pmax = fmaxf(pmax, s[reg]);
      pmax = fmaxf(pmax, __shfl_xor(pmax, 32));
      if (!__all(pmax <= m + 8.0f)) {
        float mnew = fmaxf(m, pmax);
        float al = __builtin_amdgcn_exp2f(m - mnew);
        lsum *= al;
        #pragma unroll
        for (int reg = 0; reg < 16; ++reg) { o0[reg] *= al; o1[reg] *= al; }
        m = mnew;
      }
      float p[16];
      float ls = 0.f;
      #pragma unroll
      for (int reg = 0; reg < 16; ++reg) {
        p[reg] = __builtin_amdgcn_exp2f(s[reg] - m);
        ls += p[reg];
      }
      lsum += ls;
      unsigned int c0x0 = cvtpk_bf16(p[0],  p[1]);
      unsigned int c0x1 = cvtpk_bf16(p[2],  p[3]);
      unsigned int c0y0 = cvtpk_bf16(p[4],  p[5]);
      unsigned int c0y1 = cvtpk_bf16(p[6],  p[7]);
      unsigned int c1x0 = cvtpk_bf16(p[8],  p[9]);
      unsigned int c1x1 = cvtpk_bf16(p[10], p[11]);
      unsigned int c1y0 = cvtpk_bf16(p[12], p[13]);
      unsigned int c1y1 = cvtpk_bf16(p[14], p[15]);
      asm volatile("v_permlane32_swap_b32 %0, %1" : "+v"(c0x0), "+v"(c0y0));
      asm volatile("v_permlane32_swap_b32 %0, %1" : "+v"(c0x1), "+v"(c0y1));
      asm volatile("v_permlane32_swap_b32 %0, %1" : "+v"(c1x0), "+v"(c1y0));
      asm volatile("v_permlane32_swap_b32 %0, %1" : "+v"(c1x1), "+v"(c1y1));
      union { unsigned int w[4]; bf16x8 v; } f0, f1;
      f0.w[0] = c0x0; f0.w[1] = c0x1; f0.w[2] = c0y0; f0.w[3] = c0y1;
      f1.w[0] = c1x0; f1.w[1] = c1x1; f1.w[2] = c1y0; f1.w[3] = c1y1;
      int vr0 = lq, vr1 = lq + 32;
      int cb = sub * 4 + half;
      bf16x8 vf0 = *(const bf16x8*)&Vb[vr0 * 64 + ((cb + 0) ^ (vr0 & 7)) * 8];
      bf16x8 vf1 = *(const bf16x8*)&Vb[vr0 * 64 + ((cb + 2) ^ (vr0 & 7)) * 8];
      bf16x8 vf2 = *(const bf16x8*)&Vb[vr1 * 64 + ((cb + 0) ^ (vr1 & 7)) * 8];
      bf16x8 vf3 = *(const bf16x8*)&Vb[vr1 * 64 + ((cb + 2) ^ (vr1 & 7)) * 8];
      __builtin_amdgcn_s_setprio(1);
      o0 = MFMA32(vf0, f0.v, o0);
      o0 = MFMA32(vf1, f1.v, o0);
      o1 = MFMA32(vf2, f0.v, o1);
      o1 = MFMA32(vf3, f1.v, o1);
      __builtin_amdgcn_s_setprio(0);
    }
    __syncthreads();
  }
  lsum += __shfl_xor(lsum, 32);
  float rl = 1.0f / lsum;
  int b = bh >> 3, h = bh & 7;
  unsigned short* aorow = ao + ((size_t)(b * 1024 + q0 + lq)) * 512 + h * 64;
  #pragma unroll
  for (int dt2 = 0; dt2 < 2; ++dt2) {
    #pragma unroll
    for (int g = 0; g < 4; ++g) {
      ushort4 pk;
      float v0 = (dt2 ? o1[4 * g + 0] : o0[4 * g + 0]) * rl;
      float v1 = (dt2 ? o1[4 * g + 1] : o0[4 * g + 1]) * rl;
      float v2 = (dt2 ? o1[4 * g + 2] : o0[4 * g + 2]) * rl;
      float v3 = (dt2 ? o1[4 * g + 3] : o0[4 * g + 3]) * rl;
      pk.x = f2bf(v0); pk.y = f2bf(v1); pk.z = f2bf(v2); pk.w = f2bf(v3);
      *(ushort4*)(aorow + dt2 * 32 + 8 * g + 4 * half) = pk;
    }
  }
}

// ---- kernel 6: output GEMM + bias, 8 waves (64x32/wave) -------------------
__global__ __launch_bounds__(512, 6) void k_out(const unsigned short* __restrict__ ao,
                                                const unsigned short* __restrict__ wot,
                                                const float* __restrict__ b_out,
                                                float* __restrict__ out) {
  __shared__ unsigned short As[3][128 * 32];
  __shared__ unsigned short Bs[3][128 * 32];
  int tid = threadIdx.x;
  int wid = tid >> 6, lane = tid & 63;
  int bm = blockIdx.x & 63, bn = blockIdx.x >> 6;   // 64 x 4
  int r0 = bm * 128, c0 = bn * 128;
  int lr = lane & 15, lk = (lane >> 4) * 8;
  int wr = (wid >> 2) * 64, wc = (wid & 3) * 32;
  int srow = tid >> 2, scol = (tid & 3) * 8;
  const unsigned short* gA = ao  + (size_t)(r0 + srow) * 512 + scol;
  const unsigned short* gB = wot + (size_t)(c0 + srow) * 512 + scol;
  int ldsoff = tid * 8;

  f32x4 acc[4][2];
  #pragma unroll
  for (int mi = 0; mi < 4; ++mi)
    #pragma unroll
    for (int ni = 0; ni < 2; ++ni)
      acc[mi][ni] = (f32x4){0.f, 0.f, 0.f, 0.f};

  GLD16(gA,      &As[0][ldsoff]);
  GLD16(gB,      &Bs[0][ldsoff]);
  GLD16(gA + 32, &As[1][ldsoff]);
  GLD16(gB + 32, &Bs[1][ldsoff]);

  int cur = 0, pre = 2;
  for (int t = 0; t < 16; ++t) {
    if (t < 15) asm volatile("s_waitcnt vmcnt(2)" ::: "memory");
    else        asm volatile("s_waitcnt vmcnt(0)" ::: "memory");
    __builtin_amdgcn_s_barrier();
    if (t < 14) {
      int k2 = (t + 2) * 32;
      GLD16(gA + k2, &As[pre][ldsoff]);
      GLD16(gB + k2, &Bs[pre][ldsoff]);
    }
    bf16x8 af[4], bfr[2];
    #pragma unroll
    for (int mi = 0; mi < 4; ++mi)
      af[mi] = *(const bf16x8*)&As[cur][(wr + mi * 16 + lr) * 32 + lk];
    #pragma unroll
    for (int ni = 0; ni < 2; ++ni)
      bfr[ni] = *(const bf16x8*)&Bs[cur][(wc + ni * 16 + lr) * 32 + lk];
    __builtin_amdgcn_s_setprio(1);
    #pragma unroll
    for (int mi = 0; mi < 4; ++mi)
      #pragma unroll
      for (int ni = 0; ni < 2; ++ni)
        acc[mi][ni] = MFMA16(af[mi], bfr[ni], acc[mi][ni]);
    __builtin_amdgcn_s_setprio(0);
    cur = (cur == 2) ? 0 : cur + 1;
    pre = (pre == 2) ? 0 : pre + 1;
  }

  #pragma unroll
  for (int ni = 0; ni < 2; ++ni) {
    int col = c0 + wc + ni * 16 + lr;
    float bias = b_out[col];
    #pragma unroll
    for (int mi = 0; mi < 4; ++mi)
      #pragma unroll
      for (int reg = 0; reg < 4; ++reg) {
        int row = r0 + wr + mi * 16 + (lane >> 4) * 4 + reg;
        out[(size_t)row * 512 + col] = acc[mi][ni][reg] + bias;
      }
  }
}

// ---------------------------------------------------------------------------
extern "C" void kernel_launch(void* const* d_in, const int* in_sizes, int n_in,
                              void* d_out, int out_size, void* d_ws, size_t ws_size,
                              hipStream_t stream) {
  const float* img       = (const float*)d_in[0];
  const float* tab       = (const float*)d_in[1];
  const float* w_qkv     = (const float*)d_in[2];
  const float* w_tab_qkv = (const float*)d_in[3];
  const float* w_out     = (const float*)d_in[4];
  const float* b_out     = (const float*)d_in[5];
  const float* ln_w      = (const float*)d_in[6];
  const float* ln_b      = (const float*)d_in[7];
  char* ws = (char*)d_ws;
  unsigned short* x_bf = (unsigned short*)(ws);             //  8 MiB
  unsigned short* wqt  = (unsigned short*)(ws + 8388608);   //  1.5 MiB
  unsigned short* wot  = (unsigned short*)(ws + 9961472);   //  0.5 MiB
  unsigned short* qh   = (unsigned short*)(ws + 10485760);  //  8 MiB
  unsigned short* kh   = (unsigned short*)(ws + 18874368);  //  8.5 MiB (KPAD)
  unsigned short* vt   = (unsigned short*)(ws + 27787264);  //  8.5 MiB (KPAD)
  unsigned short* ao   = (unsigned short*)(ws + 36700160);  //  8 MiB
  float* out = (float*)d_out;

  hipLaunchKernelGGL(k_pre,  dim3(2432), dim3(256), 0, stream,
                     img, tab, w_qkv, w_tab_qkv, w_out, ln_w, ln_b,
                     x_bf, wqt, wot, kh, vt);
  hipLaunchKernelGGL(k_qkv,  dim3(768),  dim3(512), 0, stream, x_bf, wqt, qh, kh, vt);
  hipLaunchKernelGGL(k_attn, dim3(256),  dim3(512), 0, stream, qh, kh, vt, ao);
  hipLaunchKernelGGL(k_out,  dim3(256),  dim3(512), 0, stream, ao, wot, b_out, out);
}